// Round 2
// baseline (6014.704 us; speedup 1.0000x reference)
//
#include <hip/hip_runtime.h>
#include <cstdint>
#include <cstddef>

// ---------------------------------------------------------------------------
// SiglipAttention with fake quantization, fp32 correctness-first baseline.
// B=16 S=729 E=1152 H=16 D=72.  Outputs (fp32): attn_output (B,S,E) then
// attn_weights (B,H,S,S).
// ---------------------------------------------------------------------------

constexpr int   cB = 16, cS = 729, cE = 1152, cH = 16, cD = 72, cDP = 80;
constexpr int   cM = cB * cS;                    // 11664 rows of (B*S)
constexpr long  cQKV  = (long)cM * cE;           // 13,436,928
constexpr long  cWN   = (long)cE * cE;           // 1,327,104
constexpr long  cVP   = (long)cB * cH * cS * cDP;// 14,929,920 (V padded D->80)
constexpr long  cRows = (long)cB * cH * cS;      // 186,624
constexpr float cScale = 0.11785113019775792f;   // 72^-0.5

// workspace layout (floats)
constexpr long OFF_SCAL = 0;                      // 16 scalar slots
constexpr long OFF_XQ   = 64;                     // quantized hidden (M,E)
constexpr long OFF_WQQ  = OFF_XQ + cQKV;
constexpr long OFF_WKQ  = OFF_WQQ + cWN;
constexpr long OFF_WVQ  = OFF_WKQ + cWN;
constexpr long OFF_WOQ  = OFF_WVQ + cWN;
constexpr long OFF_QF   = OFF_WOQ + cWN;          // q (B,H,S,D); later attn_out (B,S,E)
constexpr long OFF_KF   = OFF_QF + cQKV;          // k (B,H,S,D)
constexpr long OFF_VF   = OFF_KF + cQKV;          // v (B,H,S,80) zero-padded
constexpr long OFF_ROWM = OFF_VF + cVP;
constexpr long OFF_ROWZ = OFF_ROWM + cRows;
constexpr long WS_FLOATS = OFF_ROWZ + cRows;      // ~60.9M floats = 244 MiB

// scalar slots: 0 hid,1 wq,2 wk,3 wv,4 wo,5 q,6 k,7 v,8 minZ(+inf init),9 attn

// ---------------------------------------------------------------------------
__global__ void init_k(float* sc) {
  int t = threadIdx.x;
  if (t < 16) sc[t] = (t == 8) ? __uint_as_float(0x7f800000u) : 0.0f;
}

// grid-stride absmax over float4, result (>=0) via uint atomicMax
__global__ __launch_bounds__(256) void absmax_k(const float4* __restrict__ x, long n4,
                                                unsigned int* __restrict__ slot) {
  float m = 0.f;
  long i = (long)blockIdx.x * blockDim.x + threadIdx.x;
  long str = (long)gridDim.x * blockDim.x;
  for (; i < n4; i += str) {
    float4 v = x[i];
    m = fmaxf(m, fmaxf(fmaxf(fabsf(v.x), fabsf(v.y)), fmaxf(fabsf(v.z), fabsf(v.w))));
  }
  for (int o = 32; o; o >>= 1) m = fmaxf(m, __shfl_xor(m, o));
  __shared__ float red[4];
  int lane = threadIdx.x & 63, w = threadIdx.x >> 6;
  if (!lane) red[w] = m;
  __syncthreads();
  if (threadIdx.x == 0) {
    m = red[0];
    for (int j = 1; j < (int)(blockDim.x >> 6); ++j) m = fmaxf(m, red[j]);
    atomicMax(slot, __float_as_uint(m));
  }
}

// y = clip(rint(x/s), -qmax, qmax) * s ; s = max(maxabs,1e-8)/qmax
__global__ __launch_bounds__(256) void quant_k(const float4* __restrict__ x, float4* __restrict__ y,
                                               long n4, const float* __restrict__ slot, float qmax) {
  float s = fmaxf(*slot, 1e-8f) / qmax;
  long i = (long)blockIdx.x * blockDim.x + threadIdx.x;
  long str = (long)gridDim.x * blockDim.x;
  for (; i < n4; i += str) {
    float4 v = x[i];
    float t;
    t = rintf(v.x / s); t = fminf(fmaxf(t, -qmax), qmax); v.x = t * s;
    t = rintf(v.y / s); t = fminf(fmaxf(t, -qmax), qmax); v.y = t * s;
    t = rintf(v.z / s); t = fminf(fmaxf(t, -qmax), qmax); v.z = t * s;
    t = rintf(v.w / s); t = fminf(fmaxf(t, -qmax), qmax); v.w = t * s;
    y[i] = v;
  }
}

// ---------------------------------------------------------------------------
// C[m,n] = sum_k A[m,k]*W[n,k] + bias[n];  M=11664, N=K=1152.
// MODE 0: fp32 out, (B,H,S,D) stride 72 (q/k).  MODE 2: same, stride 80 (v).
// MODE 1: fp32 out flat (M,E) into d_out.
template <int MODE>
__global__ __launch_bounds__(256) void gemm_k(const float* __restrict__ A, const float* __restrict__ W,
                                              const float* __restrict__ bias,
                                              float* __restrict__ outF) {
  __shared__ float As[32][68];
  __shared__ float Bs[32][68];
  int m0 = blockIdx.y * 64, n0 = blockIdx.x * 64;
  int tid = threadIdx.x, ty = tid >> 4, tx = tid & 15;
  float acc[4][4] = {};
  for (int k0 = 0; k0 < cE; k0 += 32) {
    for (int i = tid; i < 512; i += 256) {
      int r = i >> 3, c = i & 7;
      int m = m0 + r;
      float4 v = make_float4(0.f, 0.f, 0.f, 0.f);
      if (m < cM) v = *(const float4*)&A[(long)m * cE + k0 + c * 4];
      As[c * 4 + 0][r] = v.x; As[c * 4 + 1][r] = v.y;
      As[c * 4 + 2][r] = v.z; As[c * 4 + 3][r] = v.w;
    }
    for (int i = tid; i < 512; i += 256) {
      int r = i >> 3, c = i & 7;
      int n = n0 + r;
      float4 v = *(const float4*)&W[(long)n * cE + k0 + c * 4];
      Bs[c * 4 + 0][r] = v.x; Bs[c * 4 + 1][r] = v.y;
      Bs[c * 4 + 2][r] = v.z; Bs[c * 4 + 3][r] = v.w;
    }
    __syncthreads();
#pragma unroll 8
    for (int kk = 0; kk < 32; ++kk) {
      float4 a4 = *(const float4*)&As[kk][ty * 4];
      float4 b4 = *(const float4*)&Bs[kk][tx * 4];
      acc[0][0] += a4.x * b4.x; acc[0][1] += a4.x * b4.y; acc[0][2] += a4.x * b4.z; acc[0][3] += a4.x * b4.w;
      acc[1][0] += a4.y * b4.x; acc[1][1] += a4.y * b4.y; acc[1][2] += a4.y * b4.z; acc[1][3] += a4.y * b4.w;
      acc[2][0] += a4.z * b4.x; acc[2][1] += a4.z * b4.y; acc[2][2] += a4.z * b4.z; acc[2][3] += a4.z * b4.w;
      acc[3][0] += a4.w * b4.x; acc[3][1] += a4.w * b4.y; acc[3][2] += a4.w * b4.z; acc[3][3] += a4.w * b4.w;
    }
    __syncthreads();
  }
#pragma unroll
  for (int i = 0; i < 4; ++i) {
    int mrow = m0 + ty * 4 + i;
    if (mrow >= cM) continue;
    int b = mrow / cS, s = mrow - b * cS;
#pragma unroll
    for (int j = 0; j < 4; ++j) {
      int n = n0 + tx * 4 + j;
      float c = acc[i][j] + bias[n];
      if (MODE == 1) {
        outF[(long)mrow * cE + n] = c;
      } else {
        int h = n / cD, d = n - h * cD;
        const int DS = (MODE == 2) ? cDP : cD;
        outF[((long)(b * cH + h) * cS + s) * (long)DS + d] = c;
      }
    }
  }
}

// ---------------------------------------------------------------------------
__device__ __forceinline__ void stage_rows(const float* __restrict__ base, int row0, int nrows,
                                           float (*Ls)[76], int tid) {
  for (int i = tid; i < nrows * 18; i += 256) {
    int r = i / 18, c = i - r * 18;
    int q = row0 + r;
    float4 v = make_float4(0.f, 0.f, 0.f, 0.f);
    if (q < cS) v = *(const float4*)&base[(long)q * cD + c * 4];
    *(float4*)&Ls[r][c * 4] = v;
  }
}

#define DOT4(A_, a_, b_) A_ += a_.x * b_.x + a_.y * b_.y + a_.z * b_.z + a_.w * b_.w

__device__ __forceinline__ void tile_dots(const float (*Qs)[76], const float (*Ks)[76],
                                          int ty, int tx, float acc[4][2]) {
#pragma unroll
  for (int d4 = 0; d4 < 18; ++d4) {
    float4 q0 = *(const float4*)&Qs[ty * 4 + 0][d4 * 4];
    float4 q1 = *(const float4*)&Qs[ty * 4 + 1][d4 * 4];
    float4 q2 = *(const float4*)&Qs[ty * 4 + 2][d4 * 4];
    float4 q3 = *(const float4*)&Qs[ty * 4 + 3][d4 * 4];
    float4 k0 = *(const float4*)&Ks[tx * 2 + 0][d4 * 4];
    float4 k1 = *(const float4*)&Ks[tx * 2 + 1][d4 * 4];
    DOT4(acc[0][0], q0, k0); DOT4(acc[0][1], q0, k1);
    DOT4(acc[1][0], q1, k0); DOT4(acc[1][1], q1, k1);
    DOT4(acc[2][0], q2, k0); DOT4(acc[2][1], q2, k1);
    DOT4(acc[3][0], q3, k0); DOT4(acc[3][1], q3, k1);
  }
}

// pass A: per-row softmax stats m,Z (online), global min Z via atomicMin
__global__ __launch_bounds__(256) void qk_passA(const float* __restrict__ qf, const float* __restrict__ kf,
                                                float* __restrict__ rowM, float* __restrict__ rowZ,
                                                unsigned int* __restrict__ minZ) {
  __shared__ float Qs[64][76];
  __shared__ float Ks[32][76];
  __shared__ unsigned int blkMin;
  int bh = blockIdx.x, q0 = blockIdx.y * 64;
  int tid = threadIdx.x, ty = tid >> 4, tx = tid & 15;
  const float* Qb = qf + (long)bh * cS * cD;
  const float* Kb = kf + (long)bh * cS * cD;
  if (tid == 0) blkMin = 0x7f800000u;
  stage_rows(Qb, q0, 64, Qs, tid);
  float m[4] = {-INFINITY, -INFINITY, -INFINITY, -INFINITY};
  float z[4] = {0.f, 0.f, 0.f, 0.f};
  for (int k0 = 0; k0 < cS; k0 += 32) {
    stage_rows(Kb, k0, 32, Ks, tid);
    __syncthreads();
    float acc[4][2] = {};
    tile_dots(Qs, Ks, ty, tx, acc);
#pragma unroll
    for (int i = 0; i < 4; ++i) {
#pragma unroll
      for (int j = 0; j < 2; ++j) {
        int k = k0 + tx * 2 + j;
        if (k < cS) {
          float l = acc[i][j] * cScale;
          if (l <= m[i]) {
            z[i] += expf(l - m[i]);
          } else {
            z[i] = z[i] * expf(m[i] - l) + 1.0f;
            m[i] = l;
          }
        }
      }
    }
    __syncthreads();
  }
  // butterfly combine across the 16 tx lanes (same rows)
#pragma unroll
  for (int o = 1; o < 16; o <<= 1) {
#pragma unroll
    for (int i = 0; i < 4; ++i) {
      float mo = __shfl_xor(m[i], o);
      float zo = __shfl_xor(z[i], o);
      float mn = fmaxf(m[i], mo);
      z[i] = z[i] * expf(m[i] - mn) + zo * expf(mo - mn);
      m[i] = mn;
    }
  }
  if (tx == 0) {
    float mz = __uint_as_float(0x7f800000u);
#pragma unroll
    for (int i = 0; i < 4; ++i) {
      int q = q0 + ty * 4 + i;
      if (q < cS) {
        rowM[(long)bh * cS + q] = m[i];
        rowZ[(long)bh * cS + q] = z[i];
        mz = fminf(mz, z[i]);
      }
    }
    atomicMin(&blkMin, __float_as_uint(mz));
  }
  __syncthreads();
  if (tid == 0) atomicMin(minZ, blkMin);
}

// pass B: recompute logits (identical math), p=exp(l-m)/Z, fq16 -> fp32 out
__global__ __launch_bounds__(256) void qk_passB(const float* __restrict__ qf, const float* __restrict__ kf,
                                                const float* __restrict__ rowM, const float* __restrict__ rowZ,
                                                const float* __restrict__ scal, float* __restrict__ P) {
  __shared__ float Qs[64][76];
  __shared__ float Ks[32][76];
  int bh = blockIdx.x, q0 = blockIdx.y * 64;
  int tid = threadIdx.x, ty = tid >> 4, tx = tid & 15;
  const float* Qb = qf + (long)bh * cS * cD;
  const float* Kb = kf + (long)bh * cS * cD;
  float minZv = scal[8];
  float pmax = fmaxf(1.0f / minZv, 1e-8f);
  float sp = pmax / 32767.0f;
  stage_rows(Qb, q0, 64, Qs, tid);
  float mr[4], zr[4];
#pragma unroll
  for (int i = 0; i < 4; ++i) {
    int q = q0 + ty * 4 + i;
    mr[i] = (q < cS) ? rowM[(long)bh * cS + q] : 0.f;
    zr[i] = (q < cS) ? rowZ[(long)bh * cS + q] : 1.f;
  }
  for (int k0 = 0; k0 < cS; k0 += 32) {
    stage_rows(Kb, k0, 32, Ks, tid);
    __syncthreads();
    float acc[4][2] = {};
    tile_dots(Qs, Ks, ty, tx, acc);
#pragma unroll
    for (int i = 0; i < 4; ++i) {
      int q = q0 + ty * 4 + i;
      if (q >= cS) continue;
#pragma unroll
      for (int j = 0; j < 2; ++j) {
        int k = k0 + tx * 2 + j;
        if (k >= cS) continue;
        float l = acc[i][j] * cScale;
        float p = expf(l - mr[i]) / zr[i];
        float n = rintf(p / sp);
        if (n > 32767.f) n = 32767.f;
        P[((long)bh * cS + q) * cS + k] = n * sp;
      }
    }
    __syncthreads();
  }
}

// PV: attn_out[b,s,h*72+d] = sum_k P[bh,q,k]*v[bh,k,d]
__global__ __launch_bounds__(256) void pv_k(const float* __restrict__ P, const float* __restrict__ vf,
                                            float* __restrict__ attn) {
  __shared__ float Ps[32][68];
  __shared__ float Vs[32][80];
  int bh = blockIdx.x, q0 = blockIdx.y * 64;
  int tid = threadIdx.x, ty = tid >> 4, tx = tid & 15;
  const float* Pb = P + (long)bh * cS * cS;
  const float* Vb = vf + (long)bh * cS * cDP;
  float acc[4][4] = {};
  float acc2[4][4] = {};
  for (int k0 = 0; k0 < cS; k0 += 32) {
    for (int i = tid; i < 2048; i += 256) {
      int r = i >> 5, kk = i & 31;
      int q = q0 + r, k = k0 + kk;
      float v = 0.f;
      if (q < cS && k < cS) v = Pb[(long)q * cS + k];
      Ps[kk][r] = v;
    }
    for (int i = tid; i < 640; i += 256) {
      int r = i / 20, c = i - r * 20;
      int k = k0 + r;
      float4 v = make_float4(0.f, 0.f, 0.f, 0.f);
      if (k < cS) v = *(const float4*)&Vb[(long)k * cDP + c * 4];
      *(float4*)&Vs[r][c * 4] = v;
    }
    __syncthreads();
#pragma unroll 8
    for (int kk = 0; kk < 32; ++kk) {
      float4 p4 = *(const float4*)&Ps[kk][ty * 4];
      float4 v4 = *(const float4*)&Vs[kk][tx * 4];
      acc[0][0] += p4.x * v4.x; acc[0][1] += p4.x * v4.y; acc[0][2] += p4.x * v4.z; acc[0][3] += p4.x * v4.w;
      acc[1][0] += p4.y * v4.x; acc[1][1] += p4.y * v4.y; acc[1][2] += p4.y * v4.z; acc[1][3] += p4.y * v4.w;
      acc[2][0] += p4.z * v4.x; acc[2][1] += p4.z * v4.y; acc[2][2] += p4.z * v4.z; acc[2][3] += p4.z * v4.w;
      acc[3][0] += p4.w * v4.x; acc[3][1] += p4.w * v4.y; acc[3][2] += p4.w * v4.z; acc[3][3] += p4.w * v4.w;
      if (tx < 2) {
        float4 w4 = *(const float4*)&Vs[kk][64 + tx * 4];
        acc2[0][0] += p4.x * w4.x; acc2[0][1] += p4.x * w4.y; acc2[0][2] += p4.x * w4.z; acc2[0][3] += p4.x * w4.w;
        acc2[1][0] += p4.y * w4.x; acc2[1][1] += p4.y * w4.y; acc2[1][2] += p4.y * w4.z; acc2[1][3] += p4.y * w4.w;
        acc2[2][0] += p4.z * w4.x; acc2[2][1] += p4.z * w4.y; acc2[2][2] += p4.z * w4.z; acc2[2][3] += p4.z * w4.w;
        acc2[3][0] += p4.w * w4.x; acc2[3][1] += p4.w * w4.y; acc2[3][2] += p4.w * w4.z; acc2[3][3] += p4.w * w4.w;
      }
    }
    __syncthreads();
  }
  int b = bh >> 4, h = bh & 15;
#pragma unroll
  for (int i = 0; i < 4; ++i) {
    int q = q0 + ty * 4 + i;
    if (q >= cS) continue;
    long base = ((long)(b * cS + q)) * cE + h * cD;
#pragma unroll
    for (int j = 0; j < 4; ++j) attn[base + tx * 4 + j] = acc[i][j];
    if (tx < 2) {
#pragma unroll
      for (int j = 0; j < 4; ++j) attn[base + 64 + tx * 4 + j] = acc2[i][j];
    }
  }
}

// ---------------------------------------------------------------------------
extern "C" void kernel_launch(void* const* d_in, const int* in_sizes, int n_in,
                              void* d_out, int out_size, void* d_ws, size_t ws_size,
                              hipStream_t stream) {
  (void)in_sizes; (void)n_in; (void)out_size;
  if (ws_size < (size_t)WS_FLOATS * sizeof(float)) return;  // need ~244 MiB scratch

  const float* hs = (const float*)d_in[0];
  const float* wq = (const float*)d_in[1];
  const float* bq = (const float*)d_in[2];
  const float* wk = (const float*)d_in[3];
  const float* bk = (const float*)d_in[4];
  const float* wv = (const float*)d_in[5];
  const float* bv = (const float*)d_in[6];
  const float* wo = (const float*)d_in[7];
  const float* bo = (const float*)d_in[8];

  float* ws = (float*)d_ws;
  float* scal = ws + OFF_SCAL;
  float* xq = ws + OFF_XQ;
  float* wqq = ws + OFF_WQQ;
  float* wkq = ws + OFF_WKQ;
  float* wvq = ws + OFF_WVQ;
  float* woq = ws + OFF_WOQ;
  float* qf = ws + OFF_QF;
  float* kf = ws + OFF_KF;
  float* vf = ws + OFF_VF;
  float* rowM = ws + OFF_ROWM;
  float* rowZ = ws + OFF_ROWZ;

  float* outb = (float*)d_out;           // attn_output fp32 (B,S,E)
  float* Pout = outb + cQKV;             // attn_weights fp32 (B,H,S,S)

  init_k<<<1, 64, 0, stream>>>(scal);
  hipMemsetAsync(vf, 0, cVP * sizeof(float), stream);  // zero V pad columns

  // per-tensor absmax of inputs
  absmax_k<<<1024, 256, 0, stream>>>((const float4*)hs, cQKV / 4, (unsigned int*)(scal + 0));
  absmax_k<<<512, 256, 0, stream>>>((const float4*)wq, cWN / 4, (unsigned int*)(scal + 1));
  absmax_k<<<512, 256, 0, stream>>>((const float4*)wk, cWN / 4, (unsigned int*)(scal + 2));
  absmax_k<<<512, 256, 0, stream>>>((const float4*)wv, cWN / 4, (unsigned int*)(scal + 3));
  absmax_k<<<512, 256, 0, stream>>>((const float4*)wo, cWN / 4, (unsigned int*)(scal + 4));

  // 16-bit fake-quant of hidden + weights
  quant_k<<<2048, 256, 0, stream>>>((const float4*)hs, (float4*)xq, cQKV / 4, scal + 0, 32767.f);
  quant_k<<<512, 256, 0, stream>>>((const float4*)wq, (float4*)wqq, cWN / 4, scal + 1, 32767.f);
  quant_k<<<512, 256, 0, stream>>>((const float4*)wk, (float4*)wkq, cWN / 4, scal + 2, 32767.f);
  quant_k<<<512, 256, 0, stream>>>((const float4*)wv, (float4*)wvq, cWN / 4, scal + 3, 32767.f);
  quant_k<<<512, 256, 0, stream>>>((const float4*)wo, (float4*)woq, cWN / 4, scal + 4, 32767.f);

  // projections -> (B,H,S,D) fp32
  dim3 ggrid(cE / 64, (cM + 63) / 64);
  gemm_k<0><<<ggrid, 256, 0, stream>>>(xq, wqq, bq, qf);
  gemm_k<0><<<ggrid, 256, 0, stream>>>(xq, wkq, bk, kf);
  gemm_k<2><<<ggrid, 256, 0, stream>>>(xq, wvq, bv, vf);

  // 8-bit fake-quant of q,k,v (in place)
  absmax_k<<<1024, 256, 0, stream>>>((const float4*)qf, cQKV / 4, (unsigned int*)(scal + 5));
  absmax_k<<<1024, 256, 0, stream>>>((const float4*)kf, cQKV / 4, (unsigned int*)(scal + 6));
  absmax_k<<<1024, 256, 0, stream>>>((const float4*)vf, cVP / 4, (unsigned int*)(scal + 7));
  quant_k<<<2048, 256, 0, stream>>>((const float4*)qf, (float4*)qf, cQKV / 4, scal + 5, 127.f);
  quant_k<<<2048, 256, 0, stream>>>((const float4*)kf, (float4*)kf, cQKV / 4, scal + 6, 127.f);
  quant_k<<<2048, 256, 0, stream>>>((const float4*)vf, (float4*)vf, cVP / 4, scal + 7, 127.f);

  // attention
  dim3 agrid(cB * cH, (cS + 63) / 64);
  qk_passA<<<agrid, 256, 0, stream>>>(qf, kf, rowM, rowZ, (unsigned int*)(scal + 8));
  qk_passB<<<agrid, 256, 0, stream>>>(qf, kf, rowM, rowZ, scal, Pout);
  pv_k<<<agrid, 256, 0, stream>>>(Pout, vf, qf /* reuse as attn_out (B,S,E) */);

  // 16-bit fake-quant of attn_out, then o-projection -> fp32 d_out
  absmax_k<<<1024, 256, 0, stream>>>((const float4*)qf, cQKV / 4, (unsigned int*)(scal + 9));
  quant_k<<<2048, 256, 0, stream>>>((const float4*)qf, (float4*)qf, cQKV / 4, scal + 9, 32767.f);
  gemm_k<1><<<ggrid, 256, 0, stream>>>(qf, woq, bo, outb);
}

// Round 3
// 2584.052 us; speedup vs baseline: 2.3276x; 2.3276x over previous
//
#include <hip/hip_runtime.h>
#include <cstdint>
#include <cstddef>

// ---------------------------------------------------------------------------
// SiglipAttention fake-quant.  B=16 S=729 E=1152 H=16 D=72.
// Outputs fp32: attn_output (B,S,E) then attn_weights (B,H,S,S).
// Round 3: attention via bf16 MFMA on integer-valued quantized q/k/v.
// ---------------------------------------------------------------------------

constexpr int   cB = 16, cS = 729, cE = 1152, cH = 16, cD = 72, cDP = 80;
constexpr int   cM = cB * cS;                    // 11664
constexpr long  cQKV  = (long)cM * cE;           // 13,436,928
constexpr long  cWN   = (long)cE * cE;           // 1,327,104
constexpr long  cVP   = (long)cB * cH * cS * cDP;// 14,929,920
constexpr float cScale = 0.11785113019775792f;   // 72^-0.5
constexpr int   cSP = 768;                       // padded S for bf16 q/k (rows)
constexpr int   cDP96 = 96;                      // padded D for MFMA K-dim

// ---- workspace byte offsets (high-water identical to round 2: 243,689,728) --
constexpr size_t B_SCAL = 0;                                   // 16 f32 slots
constexpr size_t B_XQ   = 256;                                 // xq f32 (M,E)
constexpr size_t SZ_XQ  = (size_t)cQKV * 4;                    // 53,747,712
constexpr size_t B_WQQ  = B_XQ + SZ_XQ;
constexpr size_t SZ_W   = (size_t)cWN * 4;                     // 5,308,416
constexpr size_t B_WKQ  = B_WQQ + SZ_W;
constexpr size_t B_WVQ  = B_WKQ + SZ_W;
constexpr size_t B_WOQ  = B_WVQ + SZ_W;
constexpr size_t B_QF   = B_WOQ + SZ_W;                        // q f32 (bh,S,72); later attn_out
constexpr size_t B_KF   = B_QF + SZ_XQ;
constexpr size_t B_VF   = B_KF + SZ_XQ;                        // v f32 (bh,S,80)
constexpr size_t SZ_VF  = (size_t)cVP * 4;                     // 59,719,680
constexpr size_t B_ROWM = B_VF + SZ_VF;
constexpr size_t SZ_ROW = (size_t)256 * cS * 4;                // 746,496
constexpr size_t B_ROWZ = B_ROWM + SZ_ROW;
constexpr size_t WS_TOTAL = B_ROWZ + SZ_ROW;                   // 243,689,728
// overlays (after producers are dead):
constexpr size_t B_VT = B_XQ;                                  // vT u16 (bh,80,768) = 31,457,280
constexpr size_t B_QB = B_XQ + 31457280;                       // qb u16 (bh,768,96) = 37,748,736 (ends before B_WOQ)
constexpr size_t B_KB = B_VF;                                  // kb u16 (bh,768,96)
static_assert(B_QB + 37748736 <= B_WOQ, "qb overlaps woq");

typedef __attribute__((ext_vector_type(8))) short bf16x8;
typedef __attribute__((ext_vector_type(4))) float f32x4;
#define MFMA16 __builtin_amdgcn_mfma_f32_16x16x32_bf16

__device__ __forceinline__ unsigned short f2bf(float f) {
  unsigned u = __float_as_uint(f);
  return (unsigned short)((u + 0x7fffu + ((u >> 16) & 1u)) >> 16);   // RNE
}
__device__ __forceinline__ float bf2f(unsigned short h) {
  return __uint_as_float(((unsigned)h) << 16);
}

// ---------------------------------------------------------------------------
__global__ void init_k(float* sc) {
  int t = threadIdx.x;
  if (t < 16) sc[t] = (t == 8) ? __uint_as_float(0x7f800000u) : 0.0f;
}

__global__ __launch_bounds__(256) void absmax_k(const float4* __restrict__ x, long n4,
                                                unsigned int* __restrict__ slot) {
  float m = 0.f;
  long i = (long)blockIdx.x * blockDim.x + threadIdx.x;
  long str = (long)gridDim.x * blockDim.x;
  for (; i < n4; i += str) {
    float4 v = x[i];
    m = fmaxf(m, fmaxf(fmaxf(fabsf(v.x), fabsf(v.y)), fmaxf(fabsf(v.z), fabsf(v.w))));
  }
  for (int o = 32; o; o >>= 1) m = fmaxf(m, __shfl_xor(m, o));
  __shared__ float red[4];
  int lane = threadIdx.x & 63, w = threadIdx.x >> 6;
  if (!lane) red[w] = m;
  __syncthreads();
  if (threadIdx.x == 0) {
    m = red[0];
    for (int j = 1; j < (int)(blockDim.x >> 6); ++j) m = fmaxf(m, red[j]);
    atomicMax(slot, __float_as_uint(m));
  }
}

// fq16 in fp32: y = clip(rint(x/s),-qmax,qmax)*s
__global__ __launch_bounds__(256) void quant_k(const float4* __restrict__ x, float4* __restrict__ y,
                                               long n4, const float* __restrict__ slot, float qmax) {
  float s = fmaxf(*slot, 1e-8f) / qmax;
  long i = (long)blockIdx.x * blockDim.x + threadIdx.x;
  long str = (long)gridDim.x * blockDim.x;
  for (; i < n4; i += str) {
    float4 v = x[i];
    float t;
    t = rintf(v.x / s); t = fminf(fmaxf(t, -qmax), qmax); v.x = t * s;
    t = rintf(v.y / s); t = fminf(fmaxf(t, -qmax), qmax); v.y = t * s;
    t = rintf(v.z / s); t = fminf(fmaxf(t, -qmax), qmax); v.z = t * s;
    t = rintf(v.w / s); t = fminf(fmaxf(t, -qmax), qmax); v.w = t * s;
    y[i] = v;
  }
}

// ---------------------------------------------------------------------------
// fp32 projection GEMM (unchanged, known-good).  MODE 0: (bh,S,72). MODE 2:
// (bh,S,80). MODE 1: flat (M,E).
template <int MODE>
__global__ __launch_bounds__(256) void gemm_k(const float* __restrict__ A, const float* __restrict__ W,
                                              const float* __restrict__ bias,
                                              float* __restrict__ outF) {
  __shared__ float As[32][68];
  __shared__ float Bs[32][68];
  int m0 = blockIdx.y * 64, n0 = blockIdx.x * 64;
  int tid = threadIdx.x, ty = tid >> 4, tx = tid & 15;
  float acc[4][4] = {};
  for (int k0 = 0; k0 < cE; k0 += 32) {
    for (int i = tid; i < 512; i += 256) {
      int r = i >> 3, c = i & 7;
      int m = m0 + r;
      float4 v = make_float4(0.f, 0.f, 0.f, 0.f);
      if (m < cM) v = *(const float4*)&A[(long)m * cE + k0 + c * 4];
      As[c * 4 + 0][r] = v.x; As[c * 4 + 1][r] = v.y;
      As[c * 4 + 2][r] = v.z; As[c * 4 + 3][r] = v.w;
    }
    for (int i = tid; i < 512; i += 256) {
      int r = i >> 3, c = i & 7;
      int n = n0 + r;
      float4 v = *(const float4*)&W[(long)n * cE + k0 + c * 4];
      Bs[c * 4 + 0][r] = v.x; Bs[c * 4 + 1][r] = v.y;
      Bs[c * 4 + 2][r] = v.z; Bs[c * 4 + 3][r] = v.w;
    }
    __syncthreads();
#pragma unroll 8
    for (int kk = 0; kk < 32; ++kk) {
      float4 a4 = *(const float4*)&As[kk][ty * 4];
      float4 b4 = *(const float4*)&Bs[kk][tx * 4];
      acc[0][0] += a4.x * b4.x; acc[0][1] += a4.x * b4.y; acc[0][2] += a4.x * b4.z; acc[0][3] += a4.x * b4.w;
      acc[1][0] += a4.y * b4.x; acc[1][1] += a4.y * b4.y; acc[1][2] += a4.y * b4.z; acc[1][3] += a4.y * b4.w;
      acc[2][0] += a4.z * b4.x; acc[2][1] += a4.z * b4.y; acc[2][2] += a4.z * b4.z; acc[2][3] += a4.z * b4.w;
      acc[3][0] += a4.w * b4.x; acc[3][1] += a4.w * b4.y; acc[3][2] += a4.w * b4.z; acc[3][3] += a4.w * b4.w;
    }
    __syncthreads();
  }
#pragma unroll
  for (int i = 0; i < 4; ++i) {
    int mrow = m0 + ty * 4 + i;
    if (mrow >= cM) continue;
    int b = mrow / cS, s = mrow - b * cS;
#pragma unroll
    for (int j = 0; j < 4; ++j) {
      int n = n0 + tx * 4 + j;
      float c = acc[i][j] + bias[n];
      if (MODE == 1) {
        outF[(long)mrow * cE + n] = c;
      } else {
        int h = n / cD, d = n - h * cD;
        const int DS = (MODE == 2) ? cDP : cD;
        outF[((long)(b * cH + h) * cS + s) * (long)DS + d] = c;
      }
    }
  }
}

// ---------------------------------------------------------------------------
// q/k fp32 (bh,729,72) -> 8-bit-quantized integer as bf16 (bh,768,96), zero pad
__global__ __launch_bounds__(256) void qk8_k(const float* __restrict__ src, unsigned short* __restrict__ dst,
                                             const float* __restrict__ slot) {
  float s8 = fmaxf(*slot, 1e-8f) / 127.f;
  long total2 = (long)256 * cSP * cDP96 / 2;
  long i = (long)blockIdx.x * blockDim.x + threadIdx.x;
  long str = (long)gridDim.x * blockDim.x;
  for (; i < total2; i += str) {
    long e = i * 2;
    int d = (int)(e % cDP96);
    long rem = e / cDP96;
    int s = (int)(rem % cSP);
    int bh = (int)(rem / cSP);
    float v0 = 0.f, v1 = 0.f;
    if (s < cS && d < cD) {
      const float* p = src + ((long)bh * cS + s) * cD + d;
      v0 = p[0]; v1 = p[1];
    }
    float n0 = fminf(fmaxf(rintf(v0 / s8), -127.f), 127.f);
    float n1 = fminf(fmaxf(rintf(v1 / s8), -127.f), 127.f);
    ushort2 o; o.x = f2bf(n0); o.y = f2bf(n1);
    *(ushort2*)(dst + e) = o;
  }
}

// v fp32 (bh,729,80) -> transposed 8-bit integer bf16 vT (bh,80,768)
__global__ __launch_bounds__(256) void v8T_k(const float* __restrict__ vf, unsigned short* __restrict__ vT,
                                             const float* __restrict__ slot) {
  __shared__ float T[64][85];
  int bh = blockIdx.x, k0 = blockIdx.y * 64;
  int tid = threadIdx.x;
  float s8 = fmaxf(*slot, 1e-8f) / 127.f;
  for (int e = tid; e < 64 * 80; e += 256) {
    int r = e / 80, c = e - r * 80;
    T[r][c] = (k0 + r < cS) ? vf[((long)bh * cS + k0 + r) * cDP + c] : 0.f;
  }
  __syncthreads();
  for (int e = tid; e < 64 * 80; e += 256) {
    int d = e >> 6, kk = e & 63;
    float n = fminf(fmaxf(rintf(T[kk][d] / s8), -127.f), 127.f);
    vT[((long)bh * cDP + d) * cSP + k0 + kk] = f2bf(n);
  }
}

// ---------------------------------------------------------------------------
// pass A: swapped mfma(K,Q): lane owns q = q0+ (lane&15); rows = k.
// Produces rowM (true row max), rowZ, global minZ.
__global__ __launch_bounds__(256) void qk_statsA(const unsigned short* __restrict__ qb,
                                                 const unsigned short* __restrict__ kb,
                                                 const float* __restrict__ scal,
                                                 float* __restrict__ rowM, float* __restrict__ rowZ,
                                                 unsigned int* __restrict__ minZ) {
  int bh = blockIdx.x;
  int w = threadIdx.x >> 6, lane = threadIdx.x & 63;
  int lr = lane & 15, lg = lane >> 4;
  int q0 = blockIdx.y * 64 + w * 16;
  float f = (fmaxf(scal[5], 1e-8f) / 127.f) * (fmaxf(scal[6], 1e-8f) / 127.f) * cScale;
  const unsigned short* Qp = qb + ((long)bh * cSP + q0 + lr) * cDP96 + lg * 8;
  bf16x8 qa0 = *(const bf16x8*)(Qp);
  bf16x8 qa1 = *(const bf16x8*)(Qp + 32);
  bf16x8 qa2 = *(const bf16x8*)(Qp + 64);
  const unsigned short* Kp0 = kb + ((long)bh * cSP + lr) * cDP96 + lg * 8;
  float m = -INFINITY, z = 0.f;
  for (int k0 = 0; k0 < 736; k0 += 16) {
    const unsigned short* Kp = Kp0 + (long)k0 * cDP96;
    f32x4 acc = {0.f, 0.f, 0.f, 0.f};
    acc = MFMA16(*(const bf16x8*)(Kp),      qa0, acc, 0, 0, 0);
    acc = MFMA16(*(const bf16x8*)(Kp + 32), qa1, acc, 0, 0, 0);
    acc = MFMA16(*(const bf16x8*)(Kp + 64), qa2, acc, 0, 0, 0);
    int kbase = k0 + lg * 4;
    float l0 = (kbase + 0 < cS) ? acc[0] * f : -INFINITY;
    float l1 = (kbase + 1 < cS) ? acc[1] * f : -INFINITY;
    float l2 = (kbase + 2 < cS) ? acc[2] * f : -INFINITY;
    float l3 = (kbase + 3 < cS) ? acc[3] * f : -INFINITY;
    float tm = fmaxf(fmaxf(l0, l1), fmaxf(l2, l3));
    float mn = fmaxf(m, tm);
    z = z * __expf(m - mn) + __expf(l0 - mn) + __expf(l1 - mn) + __expf(l2 - mn) + __expf(l3 - mn);
    m = mn;
  }
  // merge the 4 k-groups (same q across lane^16, lane^32)
#pragma unroll
  for (int o = 16; o <= 32; o <<= 1) {
    float mo = __shfl_xor(m, o);
    float zo = __shfl_xor(z, o);
    float mn = fmaxf(m, mo);
    z = z * __expf(m - mn) + zo * __expf(mo - mn);
    m = mn;
  }
  int q = q0 + lr;
  if (lane < 16 && q < cS) {
    rowM[(long)bh * cS + q] = m;
    rowZ[(long)bh * cS + q] = z;
  }
  float zs = (q < cS) ? z : __uint_as_float(0x7f800000u);
#pragma unroll
  for (int o = 1; o < 16; o <<= 1) zs = fminf(zs, __shfl_xor(zs, o));
  if (lane == 0) atomicMin(minZ, __float_as_uint(zs));
}

// ---------------------------------------------------------------------------
// pass B fused: P = fq16(softmax(QK*scale)) -> d_out, and attn = P @ (iv) * sv
__global__ __launch_bounds__(256) void qk_pv(const unsigned short* __restrict__ qb,
                                             const unsigned short* __restrict__ kb,
                                             const unsigned short* __restrict__ vT,
                                             const float* __restrict__ rowM, const float* __restrict__ rowZ,
                                             const float* __restrict__ scal,
                                             float* __restrict__ P, float* __restrict__ attn) {
  __shared__ float Pt[64][68];
  int bh = blockIdx.x;
  int tid = threadIdx.x, w = tid >> 6, lane = tid & 63;
  int lr = lane & 15, lg = lane >> 4;
  int q0 = blockIdx.y * 64, qw = q0 + w * 16;
  float f = (fmaxf(scal[5], 1e-8f) / 127.f) * (fmaxf(scal[6], 1e-8f) / 127.f) * cScale;
  float sv = fmaxf(scal[7], 1e-8f) / 127.f;
  float pmax = 1.0f / scal[8];                 // scal[8] = min Z  (>=1)
  float sp = fmaxf(pmax, 1e-8f) / 32767.f;
  // per-lane row params (D rows = lg*4 + r)
  float mr[4], cr[4];
#pragma unroll
  for (int r = 0; r < 4; ++r) {
    int qq = qw + lg * 4 + r;
    bool v = qq < cS;
    mr[r] = v ? rowM[(long)bh * cS + qq] : 0.f;
    float Z = v ? rowZ[(long)bh * cS + qq] : 1.f;
    cr[r] = v ? 1.0f / (Z * sp) : 0.f;         // multiplier: p/sp = exp(l-m)*cr
  }
  // hoisted Q A-frags
  const unsigned short* Qp = qb + ((long)bh * cSP + qw + lr) * cDP96 + lg * 8;
  bf16x8 qa0 = *(const bf16x8*)(Qp);
  bf16x8 qa1 = *(const bf16x8*)(Qp + 32);
  bf16x8 qa2 = *(const bf16x8*)(Qp + 64);
  f32x4 accPV[5] = {};
  for (int c = 0; c < 12; ++c) {
    int k0 = c * 64;
    // ---- QK phase: 4 n-tiles of 16 k
#pragma unroll
    for (int t = 0; t < 4; ++t) {
      const unsigned short* Kp = kb + ((long)bh * cSP + k0 + t * 16 + lr) * cDP96 + lg * 8;
      f32x4 acc = {0.f, 0.f, 0.f, 0.f};
      acc = MFMA16(qa0, *(const bf16x8*)(Kp),      acc, 0, 0, 0);
      acc = MFMA16(qa1, *(const bf16x8*)(Kp + 32), acc, 0, 0, 0);
      acc = MFMA16(qa2, *(const bf16x8*)(Kp + 64), acc, 0, 0, 0);
      int kcol = k0 + t * 16 + lr;
      bool kval = kcol < cS;
#pragma unroll
      for (int r = 0; r < 4; ++r) {
        float e = __expf(acc[r] * f - mr[r]);
        float n = rintf(e * cr[r]);
        n = fminf(n, 32767.f);
        Pt[w * 16 + lg * 4 + r][t * 16 + lr] = kval ? n * sp : 0.f;
      }
    }
    // ---- prefetch V frags for this chunk
    bf16x8 vfr[2][5];
#pragma unroll
    for (int ks = 0; ks < 2; ++ks)
#pragma unroll
      for (int dt = 0; dt < 5; ++dt)
        vfr[ks][dt] = *(const bf16x8*)(vT + ((long)bh * cDP + dt * 16 + lr) * cSP + k0 + ks * 32 + lg * 8);
    __syncthreads();
    // ---- coalesced P write (rows of up to 64 f32)
    int ncol = cS - k0; if (ncol > 64) ncol = 64;
    for (int e = tid; e < 4096; e += 256) {
      int qr = e >> 6, kk = e & 63;
      if (kk < ncol && q0 + qr < cS)
        P[((long)bh * cS + q0 + qr) * cS + k0 + kk] = Pt[qr][kk];
    }
    // ---- PV phase: A = P rows (Dekker hi/lo bf16), B = vT
#pragma unroll
    for (int ks = 0; ks < 2; ++ks) {
      const float* prow = &Pt[w * 16 + lr][ks * 32 + lg * 8];
      bf16x8 hif, lof;
#pragma unroll
      for (int i = 0; i < 8; ++i) {
        float p = prow[i];
        unsigned short hu = f2bf(p);
        float lo = p - bf2f(hu);
        hif[i] = (short)hu;
        lof[i] = (short)f2bf(lo);
      }
#pragma unroll
      for (int dt = 0; dt < 5; ++dt) {
        accPV[dt] = MFMA16(hif, vfr[ks][dt], accPV[dt], 0, 0, 0);
        accPV[dt] = MFMA16(lof, vfr[ks][dt], accPV[dt], 0, 0, 0);
      }
    }
    __syncthreads();
  }
  // epilogue: attn (B,S,E) fp32
  int b = bh >> 4, h = bh & 15;
#pragma unroll
  for (int dt = 0; dt < 5; ++dt) {
#pragma unroll
    for (int r = 0; r < 4; ++r) {
      int q = qw + lg * 4 + r, d = dt * 16 + lr;
      if (q < cS && d < cD)
        attn[((long)(b * cS + q)) * cE + h * cD + d] = accPV[dt][r] * sv;
    }
  }
}

// ---------------------------------------------------------------------------
extern "C" void kernel_launch(void* const* d_in, const int* in_sizes, int n_in,
                              void* d_out, int out_size, void* d_ws, size_t ws_size,
                              hipStream_t stream) {
  (void)in_sizes; (void)n_in; (void)out_size;
  if (ws_size < WS_TOTAL) return;

  const float* hs = (const float*)d_in[0];
  const float* wq = (const float*)d_in[1];
  const float* bq = (const float*)d_in[2];
  const float* wk = (const float*)d_in[3];
  const float* bk = (const float*)d_in[4];
  const float* wv = (const float*)d_in[5];
  const float* bv = (const float*)d_in[6];
  const float* wo = (const float*)d_in[7];
  const float* bo = (const float*)d_in[8];

  char* ws = (char*)d_ws;
  float* scal = (float*)(ws + B_SCAL);
  float* xq   = (float*)(ws + B_XQ);
  float* wqq  = (float*)(ws + B_WQQ);
  float* wkq  = (float*)(ws + B_WKQ);
  float* wvq  = (float*)(ws + B_WVQ);
  float* woq  = (float*)(ws + B_WOQ);
  float* qf   = (float*)(ws + B_QF);   // later attn_out
  float* kf   = (float*)(ws + B_KF);
  float* vf   = (float*)(ws + B_VF);
  float* rowM = (float*)(ws + B_ROWM);
  float* rowZ = (float*)(ws + B_ROWZ);
  unsigned short* vT = (unsigned short*)(ws + B_VT);
  unsigned short* qb = (unsigned short*)(ws + B_QB);
  unsigned short* kb = (unsigned short*)(ws + B_KB);

  float* outb = (float*)d_out;
  float* Pout = outb + cQKV;

  init_k<<<1, 64, 0, stream>>>(scal);
  hipMemsetAsync(vf, 0, SZ_VF, stream);  // zero V pad cols

  // absmax + fq16 of hidden and weights
  absmax_k<<<1024, 256, 0, stream>>>((const float4*)hs, cQKV / 4, (unsigned int*)(scal + 0));
  absmax_k<<<512, 256, 0, stream>>>((const float4*)wq, cWN / 4, (unsigned int*)(scal + 1));
  absmax_k<<<512, 256, 0, stream>>>((const float4*)wk, cWN / 4, (unsigned int*)(scal + 2));
  absmax_k<<<512, 256, 0, stream>>>((const float4*)wv, cWN / 4, (unsigned int*)(scal + 3));
  absmax_k<<<512, 256, 0, stream>>>((const float4*)wo, cWN / 4, (unsigned int*)(scal + 4));
  quant_k<<<2048, 256, 0, stream>>>((const float4*)hs, (float4*)xq, cQKV / 4, scal + 0, 32767.f);
  quant_k<<<512, 256, 0, stream>>>((const float4*)wq, (float4*)wqq, cWN / 4, scal + 1, 32767.f);
  quant_k<<<512, 256, 0, stream>>>((const float4*)wk, (float4*)wkq, cWN / 4, scal + 2, 32767.f);
  quant_k<<<512, 256, 0, stream>>>((const float4*)wv, (float4*)wvq, cWN / 4, scal + 3, 32767.f);
  quant_k<<<512, 256, 0, stream>>>((const float4*)wo, (float4*)woq, cWN / 4, scal + 4, 32767.f);

  // projections (fp32)
  dim3 ggrid(cE / 64, (cM + 63) / 64);
  gemm_k<0><<<ggrid, 256, 0, stream>>>(xq, wqq, bq, qf);
  gemm_k<0><<<ggrid, 256, 0, stream>>>(xq, wkq, bk, kf);
  gemm_k<2><<<ggrid, 256, 0, stream>>>(xq, wvq, bv, vf);

  // 8-bit absmax
  absmax_k<<<1024, 256, 0, stream>>>((const float4*)qf, cQKV / 4, (unsigned int*)(scal + 5));
  absmax_k<<<1024, 256, 0, stream>>>((const float4*)kf, cQKV / 4, (unsigned int*)(scal + 6));
  absmax_k<<<1024, 256, 0, stream>>>((const float4*)vf, cVP / 4, (unsigned int*)(scal + 7));

  // integer-bf16 conversions (order matters for overlays: vT before kb)
  v8T_k<<<dim3(256, 12), 256, 0, stream>>>(vf, vT, scal + 7);
  qk8_k<<<4096, 256, 0, stream>>>(qf, qb, scal + 5);
  qk8_k<<<4096, 256, 0, stream>>>(kf, kb, scal + 6);

  // attention
  qk_statsA<<<dim3(256, 12), 256, 0, stream>>>(qb, kb, scal, rowM, rowZ, (unsigned int*)(scal + 8));
  qk_pv<<<dim3(256, 12), 256, 0, stream>>>(qb, kb, vT, rowM, rowZ, scal, Pout, qf /*attn*/);

  // fq16(attn) then o-projection
  absmax_k<<<1024, 256, 0, stream>>>((const float4*)qf, cQKV / 4, (unsigned int*)(scal + 9));
  quant_k<<<2048, 256, 0, stream>>>((const float4*)qf, (float4*)qf, cQKV / 4, scal + 9, 32767.f);
  gemm_k<1><<<ggrid, 256, 0, stream>>>(qf, woq, bo, outb);
}

// Round 4
// 1550.417 us; speedup vs baseline: 3.8794x; 1.6667x over previous
//
#include <hip/hip_runtime.h>
#include <cstdint>
#include <cstddef>

// ---------------------------------------------------------------------------
// SiglipAttention fake-quant.  B=16 S=729 E=1152 H=16 D=72.
// Outputs fp32: attn_output (B,S,E) then attn_weights (B,H,S,S).
// Round 4: projections via bf16 MFMA with 3-slot Dekker hi/lo packing (K'=3456).
// ---------------------------------------------------------------------------

typedef unsigned short ushort_t;

constexpr int   cB = 16, cS = 729, cE = 1152, cH = 16, cD = 72;
constexpr int   cM = cB * cS;                    // 11664
constexpr long  cQKV  = (long)cM * cE;           // 13,436,928
constexpr long  cWN   = (long)cE * cE;           // 1,327,104
constexpr float cScale = 0.11785113019775792f;   // 72^-0.5
constexpr int   cSP = 768;                       // padded S rows for qb/kb
constexpr int   cDP96 = 96;                      // padded D for MFMA K
constexpr int   cVD = 80;                        // vT d-rows (72 used + 8 pad)
constexpr int   cKP = 3456;                      // packed K' = 3*E
constexpr int   cMH = 5888;                      // rows per M-half (46 tiles)

// ---- workspace byte offsets (total 234,817,792 <= proven 243,689,728) ------
constexpr size_t B_SCAL = 0;                                    // 16 f32
constexpr size_t B_W2O  = 256;
constexpr size_t SZ_W2  = (size_t)cE * cKP * 2;                 // 7,962,624
constexpr size_t B_W2X  = B_W2O + SZ_W2;
constexpr size_t B_A2   = B_W2X + SZ_W2;                        // 15,925,504
constexpr size_t SZ_A2  = (size_t)cMH * cKP * 2;                // 40,697,856
constexpr size_t B_RQ   = B_A2 + SZ_A2;                         // q (later k) fp32 (bh,S,72)
constexpr size_t SZ_R   = (size_t)cQKV * 4;                     // 53,747,712
constexpr size_t B_RV   = B_RQ + SZ_R;                          // v fp32; later attn_out
constexpr size_t B_VT   = B_RV + SZ_R;                          // vT bf16 (bh,80,768)
constexpr size_t SZ_VT  = (size_t)256 * cVD * cSP * 2;          // 31,457,280
constexpr size_t B_QB   = B_VT + SZ_VT;                         // qb bf16 (bh,768,96)
constexpr size_t SZ_QB  = (size_t)256 * cSP * cDP96 * 2;        // 37,748,736
constexpr size_t B_KB   = B_A2;                                 // overlay (A2 dead)
constexpr size_t B_ROWM = B_QB + SZ_QB;
constexpr size_t SZ_ROW = (size_t)256 * cS * 4;                 // 746,496
constexpr size_t B_ROWZ = B_ROWM + SZ_ROW;
constexpr size_t WS_TOTAL = B_ROWZ + SZ_ROW;
static_assert(SZ_QB <= SZ_A2, "kb overlay fits");
static_assert(WS_TOTAL <= 243689728, "stay under proven ws size");

// scalar slots: 0 hid,1 wq,2 wk,3 wv,4 wo,5 q,6 k,7 v,8 minZ,9 attn

typedef __attribute__((ext_vector_type(8))) short bf16x8;
typedef __attribute__((ext_vector_type(4))) float f32x4;
#define MFMA16 __builtin_amdgcn_mfma_f32_16x16x32_bf16

__device__ __forceinline__ unsigned short f2bf(float f) {
  unsigned u = __float_as_uint(f);
  return (unsigned short)((u + 0x7fffu + ((u >> 16) & 1u)) >> 16);   // RNE
}
__device__ __forceinline__ float bf2f(unsigned short h) {
  return __uint_as_float(((unsigned)h) << 16);
}
__device__ __forceinline__ void gload16(const void* g, void* l) {
  __builtin_amdgcn_global_load_lds((const __attribute__((address_space(1))) unsigned int*)g,
                                   (__attribute__((address_space(3))) unsigned int*)l, 16, 0, 0);
}

// ---------------------------------------------------------------------------
__global__ void init_k(float* sc) {
  int t = threadIdx.x;
  if (t < 16) sc[t] = (t == 8) ? __uint_as_float(0x7f800000u) : 0.0f;
}

__global__ __launch_bounds__(256) void absmax_k(const float4* __restrict__ x, long n4,
                                                unsigned int* __restrict__ slot) {
  float m = 0.f;
  long i = (long)blockIdx.x * blockDim.x + threadIdx.x;
  long str = (long)gridDim.x * blockDim.x;
  for (; i < n4; i += str) {
    float4 v = x[i];
    m = fmaxf(m, fmaxf(fmaxf(fabsf(v.x), fabsf(v.y)), fmaxf(fabsf(v.z), fabsf(v.w))));
  }
  for (int o = 32; o; o >>= 1) m = fmaxf(m, __shfl_xor(m, o));
  __shared__ float red[4];
  int lane = threadIdx.x & 63, w = threadIdx.x >> 6;
  if (!lane) red[w] = m;
  __syncthreads();
  if (threadIdx.x == 0) {
    m = red[0];
    for (int j = 1; j < (int)(blockDim.x >> 6); ++j) m = fmaxf(m, red[j]);
    atomicMax(slot, __float_as_uint(m));
  }
}

// ---------------------------------------------------------------------------
// fq16 + Dekker hi/lo pack.  A slots per k: (h,h,l).  W slots per k: (h,l,h).
__global__ __launch_bounds__(256) void packA_k(const float* __restrict__ src, const float* __restrict__ slot,
                                               ushort_t* __restrict__ A2, int m_base) {
  float s = fmaxf(*slot, 1e-8f) / 32767.f;
  int i = blockIdx.x * 256 + threadIdx.x;       // < cMH * 144
  int r = i / 144, c8 = i - r * 144;
  int m = m_base + r; if (m >= cM) m = cM - 1;
  const float4* p = (const float4*)(src + (long)m * cE + c8 * 8);
  float4 v0 = p[0], v1 = p[1];
  float xv[8] = {v0.x, v0.y, v0.z, v0.w, v1.x, v1.y, v1.z, v1.w};
  ushort_t o[24] __attribute__((aligned(16)));
#pragma unroll
  for (int j = 0; j < 8; ++j) {
    float t = rintf(xv[j] / s); t = fminf(fmaxf(t, -32767.f), 32767.f);
    float v = t * s;
    ushort_t h = f2bf(v);
    ushort_t l = f2bf(v - bf2f(h));
    o[j * 3 + 0] = h; o[j * 3 + 1] = h; o[j * 3 + 2] = l;
  }
  ushort_t* dst = A2 + (long)r * cKP + c8 * 24;
  *(uint4*)(dst) = *(const uint4*)(o);
  *(uint4*)(dst + 8) = *(const uint4*)(o + 8);
  *(uint4*)(dst + 16) = *(const uint4*)(o + 16);
}

__global__ __launch_bounds__(256) void packW_k(const float* __restrict__ w, const float* __restrict__ slot,
                                               ushort_t* __restrict__ W2) {
  float s = fmaxf(*slot, 1e-8f) / 32767.f;
  int i = blockIdx.x * 256 + threadIdx.x;       // < cE * 144
  int r = i / 144, c8 = i - r * 144;
  const float4* p = (const float4*)(w + (long)r * cE + c8 * 8);
  float4 v0 = p[0], v1 = p[1];
  float xv[8] = {v0.x, v0.y, v0.z, v0.w, v1.x, v1.y, v1.z, v1.w};
  ushort_t o[24] __attribute__((aligned(16)));
#pragma unroll
  for (int j = 0; j < 8; ++j) {
    float t = rintf(xv[j] / s); t = fminf(fmaxf(t, -32767.f), 32767.f);
    float v = t * s;
    ushort_t h = f2bf(v);
    ushort_t l = f2bf(v - bf2f(h));
    o[j * 3 + 0] = h; o[j * 3 + 1] = l; o[j * 3 + 2] = h;
  }
  ushort_t* dst = W2 + (long)r * cKP + c8 * 24;
  *(uint4*)(dst) = *(const uint4*)(o);
  *(uint4*)(dst + 8) = *(const uint4*)(o + 8);
  *(uint4*)(dst + 16) = *(const uint4*)(o + 16);
}

// ---------------------------------------------------------------------------
// bf16 MFMA GEMM: C[m,n] = sum_k' A2[m,k']*W2[n,k'] + bias[n].
// 128x128 tile, BK=32, 4 waves 2x2 (64x64 each), global_load_lds staging,
// 16B-unit XOR swizzle (u ^= row>>1) on both store-source and ds_read.
// OM 0: fp32 (bh,S,72).  OM 1: fp32 flat (M,E).
template <int OM>
__global__ __launch_bounds__(256) void mgemm_k(const ushort_t* __restrict__ A2, const ushort_t* __restrict__ W2,
                                               const float* __restrict__ bias, float* __restrict__ out,
                                               int m_base) {
  __shared__ ushort_t As[4096];   // 128 rows x 32 bf16
  __shared__ ushort_t Bs[4096];
  int tid = threadIdx.x, w = tid >> 6, lane = tid & 63;
  int lr = lane & 15, kc = lane >> 4;
  int mt = blockIdx.y * 128, nt = blockIdx.x * 128;
  int wr = (w >> 1) * 64, wc = (w & 1) * 64;

  // staging map: phase p linear LDS byte = p*4096 + w*1024 + lane*16
  int sb0 = w * 1024 + lane * 16;
  int row0 = sb0 >> 6, c0 = (((sb0 >> 4) & 3) - (row0 >> 1)) & 3;
  int sb1 = 4096 + w * 1024 + lane * 16;
  int row1 = sb1 >> 6, c1 = (((sb1 >> 4) & 3) - (row1 >> 1)) & 3;
  const ushort_t* Ag0 = A2 + (long)(mt + row0) * cKP + c0 * 8;
  const ushort_t* Ag1 = A2 + (long)(mt + row1) * cKP + c1 * 8;
  const ushort_t* Bg0 = W2 + (long)(nt + row0) * cKP + c0 * 8;
  const ushort_t* Bg1 = W2 + (long)(nt + row1) * cKP + c1 * 8;
  ushort_t* lA0 = &As[w * 512];          // phase bases (ushort units)
  ushort_t* lA1 = &As[2048 + w * 512];
  ushort_t* lB0 = &Bs[w * 512];
  ushort_t* lB1 = &Bs[2048 + w * 512];

  // ds_read offsets (ushort units), constant over K
  int aoff[4], boff[4];
#pragma unroll
  for (int i = 0; i < 4; ++i) {
    int ar = wr + i * 16 + lr;
    aoff[i] = ar * 32 + (((kc + (ar >> 1)) & 3) * 8);
    int br = wc + i * 16 + lr;
    boff[i] = br * 32 + (((kc + (br >> 1)) & 3) * 8);
  }

  f32x4 acc[4][4] = {};
  for (int kk = 0; kk < cKP / 32; ++kk) {
    gload16(Ag0 + kk * 32, lA0);
    gload16(Ag1 + kk * 32, lA1);
    gload16(Bg0 + kk * 32, lB0);
    gload16(Bg1 + kk * 32, lB1);
    __syncthreads();
    bf16x8 af[4], bfr[4];
#pragma unroll
    for (int i = 0; i < 4; ++i) af[i] = *(const bf16x8*)&As[aoff[i]];
#pragma unroll
    for (int j = 0; j < 4; ++j) bfr[j] = *(const bf16x8*)&Bs[boff[j]];
#pragma unroll
    for (int i = 0; i < 4; ++i)
#pragma unroll
      for (int j = 0; j < 4; ++j)
        acc[i][j] = MFMA16(af[i], bfr[j], acc[i][j], 0, 0, 0);
    __syncthreads();
  }

  // epilogue: C row = wr+i*16+kc*4+reg, col = wc+j*16+lr
#pragma unroll
  for (int i = 0; i < 4; ++i) {
#pragma unroll
    for (int r = 0; r < 4; ++r) {
      int m = m_base + mt + wr + i * 16 + kc * 4 + r;
      if (m >= cM) continue;
      int b = m / cS, s = m - b * cS;
#pragma unroll
      for (int j = 0; j < 4; ++j) {
        int n = nt + wc + j * 16 + lr;
        float cv = acc[i][j][r] + bias[n];
        if (OM == 1) {
          out[(long)m * cE + n] = cv;
        } else {
          int h = n / cD, d = n - h * cD;
          out[((long)(b * cH + h) * cS + s) * cD + d] = cv;
        }
      }
    }
  }
}

// ---------------------------------------------------------------------------
// q/k fp32 (bh,729,72) -> 8-bit integer as bf16 (bh,768,96), zero pad
__global__ __launch_bounds__(256) void qk8_k(const float* __restrict__ src, ushort_t* __restrict__ dst,
                                             const float* __restrict__ slot) {
  float s8 = fmaxf(*slot, 1e-8f) / 127.f;
  long total2 = (long)256 * cSP * cDP96 / 2;
  long i = (long)blockIdx.x * blockDim.x + threadIdx.x;
  long str = (long)gridDim.x * blockDim.x;
  for (; i < total2; i += str) {
    long e = i * 2;
    int d = (int)(e % cDP96);
    long rem = e / cDP96;
    int s = (int)(rem % cSP);
    int bh = (int)(rem / cSP);
    float v0 = 0.f, v1 = 0.f;
    if (s < cS && d < cD) {
      const float* p = src + ((long)bh * cS + s) * cD + d;
      v0 = p[0]; v1 = p[1];
    }
    float n0 = fminf(fmaxf(rintf(v0 / s8), -127.f), 127.f);
    float n1 = fminf(fmaxf(rintf(v1 / s8), -127.f), 127.f);
    ushort2 o; o.x = f2bf(n0); o.y = f2bf(n1);
    *(ushort2*)(dst + e) = o;
  }
}

// v fp32 (bh,729,72) -> transposed 8-bit integer bf16 vT (bh,80,768)
__global__ __launch_bounds__(256) void v8T_k(const float* __restrict__ vf, ushort_t* __restrict__ vT,
                                             const float* __restrict__ slot) {
  __shared__ float T[64][73];
  int bh = blockIdx.x, k0 = blockIdx.y * 64;
  int tid = threadIdx.x;
  float s8 = fmaxf(*slot, 1e-8f) / 127.f;
  for (int e = tid; e < 64 * 72; e += 256) {
    int r = e / 72, c = e - r * 72;
    T[r][c] = (k0 + r < cS) ? vf[((long)bh * cS + k0 + r) * cD + c] : 0.f;
  }
  __syncthreads();
  for (int e = tid; e < 64 * 80; e += 256) {
    int d = e >> 6, kk = e & 63;
    float val = (d < cD && k0 + kk < cS) ? T[kk][d] : 0.f;
    float n = fminf(fmaxf(rintf(val / s8), -127.f), 127.f);
    vT[((long)bh * cVD + d) * cSP + k0 + kk] = f2bf(n);
  }
}

// ---------------------------------------------------------------------------
// pass A: swapped mfma(K,Q) -> per-row m,Z; global min Z.
__global__ __launch_bounds__(256) void qk_statsA(const ushort_t* __restrict__ qb,
                                                 const ushort_t* __restrict__ kb,
                                                 const float* __restrict__ scal,
                                                 float* __restrict__ rowM, float* __restrict__ rowZ,
                                                 unsigned int* __restrict__ minZ) {
  int bh = blockIdx.x;
  int w = threadIdx.x >> 6, lane = threadIdx.x & 63;
  int lr = lane & 15, lg = lane >> 4;
  int q0 = blockIdx.y * 64 + w * 16;
  float f = (fmaxf(scal[5], 1e-8f) / 127.f) * (fmaxf(scal[6], 1e-8f) / 127.f) * cScale;
  const ushort_t* Qp = qb + ((long)bh * cSP + q0 + lr) * cDP96 + lg * 8;
  bf16x8 qa0 = *(const bf16x8*)(Qp);
  bf16x8 qa1 = *(const bf16x8*)(Qp + 32);
  bf16x8 qa2 = *(const bf16x8*)(Qp + 64);
  const ushort_t* Kp0 = kb + ((long)bh * cSP + lr) * cDP96 + lg * 8;
  float m = -INFINITY, z = 0.f;
  for (int k0 = 0; k0 < 736; k0 += 16) {
    const ushort_t* Kp = Kp0 + (long)k0 * cDP96;
    f32x4 acc = {0.f, 0.f, 0.f, 0.f};
    acc = MFMA16(*(const bf16x8*)(Kp),      qa0, acc, 0, 0, 0);
    acc = MFMA16(*(const bf16x8*)(Kp + 32), qa1, acc, 0, 0, 0);
    acc = MFMA16(*(const bf16x8*)(Kp + 64), qa2, acc, 0, 0, 0);
    int kbase = k0 + lg * 4;
    float l0 = (kbase + 0 < cS) ? acc[0] * f : -INFINITY;
    float l1 = (kbase + 1 < cS) ? acc[1] * f : -INFINITY;
    float l2 = (kbase + 2 < cS) ? acc[2] * f : -INFINITY;
    float l3 = (kbase + 3 < cS) ? acc[3] * f : -INFINITY;
    float tm = fmaxf(fmaxf(l0, l1), fmaxf(l2, l3));
    float mn = fmaxf(m, tm);
    z = z * __expf(m - mn) + __expf(l0 - mn) + __expf(l1 - mn) + __expf(l2 - mn) + __expf(l3 - mn);
    m = mn;
  }
#pragma unroll
  for (int o = 16; o <= 32; o <<= 1) {
    float mo = __shfl_xor(m, o);
    float zo = __shfl_xor(z, o);
    float mn = fmaxf(m, mo);
    z = z * __expf(m - mn) + zo * __expf(mo - mn);
    m = mn;
  }
  int q = q0 + lr;
  if (lane < 16 && q < cS) {
    rowM[(long)bh * cS + q] = m;
    rowZ[(long)bh * cS + q] = z;
  }
  float zs = (q < cS) ? z : __uint_as_float(0x7f800000u);
#pragma unroll
  for (int o = 1; o < 16; o <<= 1) zs = fminf(zs, __shfl_xor(zs, o));
  if (lane == 0) atomicMin(minZ, __float_as_uint(zs));
}

// ---------------------------------------------------------------------------
// pass B fused: P = fq16(softmax) -> d_out, attn = P @ v * sv -> Rv
__global__ __launch_bounds__(256) void qk_pv(const ushort_t* __restrict__ qb,
                                             const ushort_t* __restrict__ kb,
                                             const ushort_t* __restrict__ vT,
                                             const float* __restrict__ rowM, const float* __restrict__ rowZ,
                                             const float* __restrict__ scal,
                                             float* __restrict__ P, float* __restrict__ attn) {
  __shared__ float Pt[64][68];
  int bh = blockIdx.x;
  int tid = threadIdx.x, w = tid >> 6, lane = tid & 63;
  int lr = lane & 15, lg = lane >> 4;
  int q0 = blockIdx.y * 64, qw = q0 + w * 16;
  float f = (fmaxf(scal[5], 1e-8f) / 127.f) * (fmaxf(scal[6], 1e-8f) / 127.f) * cScale;
  float sv = fmaxf(scal[7], 1e-8f) / 127.f;
  float pmax = 1.0f / scal[8];
  float sp = fmaxf(pmax, 1e-8f) / 32767.f;
  float mr[4], cr[4];
#pragma unroll
  for (int r = 0; r < 4; ++r) {
    int qq = qw + lg * 4 + r;
    bool v = qq < cS;
    mr[r] = v ? rowM[(long)bh * cS + qq] : 0.f;
    float Z = v ? rowZ[(long)bh * cS + qq] : 1.f;
    cr[r] = v ? 1.0f / (Z * sp) : 0.f;
  }
  const ushort_t* Qp = qb + ((long)bh * cSP + qw + lr) * cDP96 + lg * 8;
  bf16x8 qa0 = *(const bf16x8*)(Qp);
  bf16x8 qa1 = *(const bf16x8*)(Qp + 32);
  bf16x8 qa2 = *(const bf16x8*)(Qp + 64);
  f32x4 accPV[5] = {};
  for (int c = 0; c < 12; ++c) {
    int k0 = c * 64;
#pragma unroll
    for (int t = 0; t < 4; ++t) {
      const ushort_t* Kp = kb + ((long)bh * cSP + k0 + t * 16 + lr) * cDP96 + lg * 8;
      f32x4 acc = {0.f, 0.f, 0.f, 0.f};
      acc = MFMA16(qa0, *(const bf16x8*)(Kp),      acc, 0, 0, 0);
      acc = MFMA16(qa1, *(const bf16x8*)(Kp + 32), acc, 0, 0, 0);
      acc = MFMA16(qa2, *(const bf16x8*)(Kp + 64), acc, 0, 0, 0);
      int kcol = k0 + t * 16 + lr;
      bool kval = kcol < cS;
#pragma unroll
      for (int r = 0; r < 4; ++r) {
        float e = __expf(acc[r] * f - mr[r]);
        float n = rintf(e * cr[r]);
        n = fminf(n, 32767.f);
        Pt[w * 16 + lg * 4 + r][t * 16 + lr] = kval ? n * sp : 0.f;
      }
    }
    bf16x8 vfr[2][5];
#pragma unroll
    for (int ks = 0; ks < 2; ++ks)
#pragma unroll
      for (int dt = 0; dt < 5; ++dt)
        vfr[ks][dt] = *(const bf16x8*)(vT + ((long)bh * cVD + dt * 16 + lr) * cSP + k0 + ks * 32 + lg * 8);
    __syncthreads();
    int ncol = cS - k0; if (ncol > 64) ncol = 64;
    for (int e = tid; e < 4096; e += 256) {
      int qr = e >> 6, kk = e & 63;
      if (kk < ncol && q0 + qr < cS)
        P[((long)bh * cS + q0 + qr) * cS + k0 + kk] = Pt[qr][kk];
    }
#pragma unroll
    for (int ks = 0; ks < 2; ++ks) {
      const float* prow = &Pt[w * 16 + lr][ks * 32 + lg * 8];
      bf16x8 hif, lof;
#pragma unroll
      for (int i = 0; i < 8; ++i) {
        float p = prow[i];
        unsigned short hu = f2bf(p);
        float lo = p - bf2f(hu);
        hif[i] = (short)hu;
        lof[i] = (short)f2bf(lo);
      }
#pragma unroll
      for (int dt = 0; dt < 5; ++dt) {
        accPV[dt] = MFMA16(hif, vfr[ks][dt], accPV[dt], 0, 0, 0);
        accPV[dt] = MFMA16(lof, vfr[ks][dt], accPV[dt], 0, 0, 0);
      }
    }
    __syncthreads();
  }
  int b = bh >> 4, h = bh & 15;
#pragma unroll
  for (int dt = 0; dt < 5; ++dt) {
#pragma unroll
    for (int r = 0; r < 4; ++r) {
      int q = qw + lg * 4 + r, d = dt * 16 + lr;
      if (q < cS && d < cD)
        attn[((long)(b * cS + q)) * cE + h * cD + d] = accPV[dt][r] * sv;
    }
  }
}

// ---------------------------------------------------------------------------
extern "C" void kernel_launch(void* const* d_in, const int* in_sizes, int n_in,
                              void* d_out, int out_size, void* d_ws, size_t ws_size,
                              hipStream_t stream) {
  (void)in_sizes; (void)n_in; (void)out_size;
  if (ws_size < WS_TOTAL) return;

  const float* hs = (const float*)d_in[0];
  const float* wq = (const float*)d_in[1];
  const float* bq = (const float*)d_in[2];
  const float* wk = (const float*)d_in[3];
  const float* bk = (const float*)d_in[4];
  const float* wv = (const float*)d_in[5];
  const float* bv = (const float*)d_in[6];
  const float* wo = (const float*)d_in[7];
  const float* bo = (const float*)d_in[8];

  char* ws = (char*)d_ws;
  float* scal = (float*)(ws + B_SCAL);
  ushort_t* W2O = (ushort_t*)(ws + B_W2O);
  ushort_t* W2X = (ushort_t*)(ws + B_W2X);
  ushort_t* A2  = (ushort_t*)(ws + B_A2);
  float* Rq   = (float*)(ws + B_RQ);
  float* Rv   = (float*)(ws + B_RV);
  ushort_t* vT = (ushort_t*)(ws + B_VT);
  ushort_t* qb = (ushort_t*)(ws + B_QB);
  ushort_t* kb = (ushort_t*)(ws + B_KB);
  float* rowM = (float*)(ws + B_ROWM);
  float* rowZ = (float*)(ws + B_ROWZ);

  float* outb = (float*)d_out;
  float* Pout = outb + cQKV;

  dim3 ggrid(cE / 128, cMH / 128);   // (9, 46)
  dim3 agrid(cB * cH, 12);

  init_k<<<1, 64, 0, stream>>>(scal);

  // absmax of inputs
  absmax_k<<<1024, 256, 0, stream>>>((const float4*)hs, cQKV / 4, (unsigned int*)(scal + 0));
  absmax_k<<<512, 256, 0, stream>>>((const float4*)wq, cWN / 4, (unsigned int*)(scal + 1));
  absmax_k<<<512, 256, 0, stream>>>((const float4*)wk, cWN / 4, (unsigned int*)(scal + 2));
  absmax_k<<<512, 256, 0, stream>>>((const float4*)wv, cWN / 4, (unsigned int*)(scal + 3));
  absmax_k<<<512, 256, 0, stream>>>((const float4*)wo, cWN / 4, (unsigned int*)(scal + 4));

  packW_k<<<648, 256, 0, stream>>>(wo, scal + 4, W2O);

  // ---- V projection
  packW_k<<<648, 256, 0, stream>>>(wv, scal + 3, W2X);
  packA_k<<<3312, 256, 0, stream>>>(hs, scal + 0, A2, 0);
  mgemm_k<0><<<ggrid, 256, 0, stream>>>(A2, W2X, bv, Rv, 0);
  packA_k<<<3312, 256, 0, stream>>>(hs, scal + 0, A2, cMH);
  mgemm_k<0><<<ggrid, 256, 0, stream>>>(A2, W2X, bv, Rv, cMH);
  absmax_k<<<1024, 256, 0, stream>>>((const float4*)Rv, cQKV / 4, (unsigned int*)(scal + 7));
  v8T_k<<<dim3(256, 12), 256, 0, stream>>>(Rv, vT, scal + 7);

  // ---- Q projection
  packW_k<<<648, 256, 0, stream>>>(wq, scal + 1, W2X);
  packA_k<<<3312, 256, 0, stream>>>(hs, scal + 0, A2, 0);
  mgemm_k<0><<<ggrid, 256, 0, stream>>>(A2, W2X, bq, Rq, 0);
  packA_k<<<3312, 256, 0, stream>>>(hs, scal + 0, A2, cMH);
  mgemm_k<0><<<ggrid, 256, 0, stream>>>(A2, W2X, bq, Rq, cMH);
  absmax_k<<<1024, 256, 0, stream>>>((const float4*)Rq, cQKV / 4, (unsigned int*)(scal + 5));
  qk8_k<<<4096, 256, 0, stream>>>(Rq, qb, scal + 5);

  // ---- K projection (reuse Rq)
  packW_k<<<648, 256, 0, stream>>>(wk, scal + 2, W2X);
  packA_k<<<3312, 256, 0, stream>>>(hs, scal + 0, A2, 0);
  mgemm_k<0><<<ggrid, 256, 0, stream>>>(A2, W2X, bk, Rq, 0);
  packA_k<<<3312, 256, 0, stream>>>(hs, scal + 0, A2, cMH);
  mgemm_k<0><<<ggrid, 256, 0, stream>>>(A2, W2X, bk, Rq, cMH);
  absmax_k<<<1024, 256, 0, stream>>>((const float4*)Rq, cQKV / 4, (unsigned int*)(scal + 6));
  qk8_k<<<4096, 256, 0, stream>>>(Rq, kb, scal + 6);   // kb overlays A2 (dead)

  // ---- attention
  qk_statsA<<<agrid, 256, 0, stream>>>(qb, kb, scal, rowM, rowZ, (unsigned int*)(scal + 8));
  qk_pv<<<agrid, 256, 0, stream>>>(qb, kb, vT, rowM, rowZ, scal, Pout, Rv);

  // ---- O projection (attn in Rv; A2 region free again after qk_pv)
  absmax_k<<<1024, 256, 0, stream>>>((const float4*)Rv, cQKV / 4, (unsigned int*)(scal + 9));
  packA_k<<<3312, 256, 0, stream>>>(Rv, scal + 9, A2, 0);
  mgemm_k<1><<<ggrid, 256, 0, stream>>>(A2, W2O, bo, outb, 0);
  packA_k<<<3312, 256, 0, stream>>>(Rv, scal + 9, A2, cMH);
  mgemm_k<1><<<ggrid, 256, 0, stream>>>(A2, W2O, bo, outb, cMH);
}

// Round 5
// 1524.073 us; speedup vs baseline: 3.9465x; 1.0173x over previous
//
#include <hip/hip_runtime.h>
#include <cstdint>
#include <cstddef>

// ---------------------------------------------------------------------------
// SiglipAttention fake-quant.  B=16 S=729 E=1152 H=16 D=72.
// Outputs fp32: attn_output (B,S,E) then attn_weights (B,H,S,S).
// Round 5: single packed A, z-merged dbuf MFMA GEMM, wave-independent qk_pv,
//          fused absmax epilogues, d_out P-region used as fp32 scratch.
// ---------------------------------------------------------------------------

typedef unsigned short ushort_t;

constexpr int   cB = 16, cS = 729, cE = 1152, cH = 16, cD = 72;
constexpr int   cM = cB * cS;                    // 11664
constexpr long  cQKV  = (long)cM * cE;           // 13,436,928
constexpr long  cWN   = (long)cE * cE;           // 1,327,104
constexpr float cScale = 0.11785113019775792f;   // 72^-0.5
constexpr int   cSP = 768;                       // padded S rows for qb/kb
constexpr int   cDP96 = 96;                      // padded D for MFMA K
constexpr int   cVD = 80;                        // vT d-rows (72 used + 8 pad)
constexpr int   cKP = 3456;                      // packed K' = 3*E
constexpr int   cMF = 11776;                     // padded M (92 tiles of 128)

// ---- workspace byte offsets (total ~221.7 MB <= proven 243.7 MB) -----------
constexpr size_t B_SCAL = 0;                                    // 16 f32
constexpr size_t SZ_W2  = (size_t)cE * cKP * 2;                 // 7,962,624
constexpr size_t B_W2O  = 256;
constexpr size_t B_W2Q  = B_W2O + SZ_W2;                        // W2Q,K,V contiguous
constexpr size_t B_A2   = B_W2Q + 3 * SZ_W2;
constexpr size_t SZ_A2  = (size_t)cMF * cKP * 2;                // 81,395,712
constexpr size_t B_VT   = B_A2 + SZ_A2;
constexpr size_t SZ_VT  = (size_t)256 * cVD * cSP * 2;          // 31,457,280
constexpr size_t B_QB   = B_VT + SZ_VT;
constexpr size_t SZ_QB  = (size_t)256 * cSP * cDP96 * 2;        // 37,748,736
constexpr size_t B_KB   = B_QB + SZ_QB;
constexpr size_t B_ROWM = B_KB + SZ_QB;
constexpr size_t SZ_ROW = (size_t)256 * cS * 4;                 // 746,496
constexpr size_t B_ROWZ = B_ROWM + SZ_ROW;
constexpr size_t WS_TOTAL = B_ROWZ + SZ_ROW;                    // 221,694,208
static_assert(WS_TOTAL <= 243689728, "stay under proven ws size");

// scalar slots: 0 hid,1 wq,2 wk,3 wv,4 wo,5 q,6 k,7 v,8 minZ,9 attn

typedef __attribute__((ext_vector_type(8))) short bf16x8;
typedef __attribute__((ext_vector_type(4))) float f32x4;
#define MFMA16 __builtin_amdgcn_mfma_f32_16x16x32_bf16

__device__ __forceinline__ unsigned short f2bf(float f) {
  unsigned u = __float_as_uint(f);
  return (unsigned short)((u + 0x7fffu + ((u >> 16) & 1u)) >> 16);   // RNE
}
__device__ __forceinline__ float bf2f(unsigned short h) {
  return __uint_as_float(((unsigned)h) << 16);
}
__device__ __forceinline__ void gload16(const void* g, void* l) {
  __builtin_amdgcn_global_load_lds((const __attribute__((address_space(1))) unsigned int*)g,
                                   (__attribute__((address_space(3))) unsigned int*)l, 16, 0, 0);
}

// ---------------------------------------------------------------------------
__global__ void init_k(float* sc) {
  int t = threadIdx.x;
  if (t < 16) sc[t] = (t == 8) ? __uint_as_float(0x7f800000u) : 0.0f;
}

__global__ __launch_bounds__(256) void absmax_k(const float4* __restrict__ x, long n4,
                                                unsigned int* __restrict__ slot) {
  float m = 0.f;
  long i = (long)blockIdx.x * blockDim.x + threadIdx.x;
  long str = (long)gridDim.x * blockDim.x;
  for (; i < n4; i += str) {
    float4 v = x[i];
    m = fmaxf(m, fmaxf(fmaxf(fabsf(v.x), fabsf(v.y)), fmaxf(fabsf(v.z), fabsf(v.w))));
  }
  for (int o = 32; o; o >>= 1) m = fmaxf(m, __shfl_xor(m, o));
  __shared__ float red[4];
  int lane = threadIdx.x & 63, w = threadIdx.x >> 6;
  if (!lane) red[w] = m;
  __syncthreads();
  if (threadIdx.x == 0) {
    m = red[0];
    for (int j = 1; j < (int)(blockDim.x >> 6); ++j) m = fmaxf(m, red[j]);
    atomicMax(slot, __float_as_uint(m));
  }
}

// ---------------------------------------------------------------------------
// fq16 + Dekker hi/lo pack.  A slots per k: (h,h,l).  W slots per k: (h,l,h).
__global__ __launch_bounds__(256) void packA_k(const float* __restrict__ src, const float* __restrict__ slot,
                                               ushort_t* __restrict__ A2) {
  float s = fmaxf(*slot, 1e-8f) / 32767.f;
  int i = blockIdx.x * 256 + threadIdx.x;       // < cMF * 144
  int r = i / 144, c8 = i - r * 144;
  int m = r; if (m >= cM) m = cM - 1;
  const float4* p = (const float4*)(src + (long)m * cE + c8 * 8);
  float4 v0 = p[0], v1 = p[1];
  float xv[8] = {v0.x, v0.y, v0.z, v0.w, v1.x, v1.y, v1.z, v1.w};
  ushort_t o[24] __attribute__((aligned(16)));
#pragma unroll
  for (int j = 0; j < 8; ++j) {
    float t = rintf(xv[j] / s); t = fminf(fmaxf(t, -32767.f), 32767.f);
    float v = t * s;
    ushort_t h = f2bf(v);
    ushort_t l = f2bf(v - bf2f(h));
    o[j * 3 + 0] = h; o[j * 3 + 1] = h; o[j * 3 + 2] = l;
  }
  ushort_t* dst = A2 + (long)r * cKP + c8 * 24;
  *(uint4*)(dst) = *(const uint4*)(o);
  *(uint4*)(dst + 8) = *(const uint4*)(o + 8);
  *(uint4*)(dst + 16) = *(const uint4*)(o + 16);
}

__global__ __launch_bounds__(256) void packW_k(const float* __restrict__ w, const float* __restrict__ slot,
                                               ushort_t* __restrict__ W2) {
  float s = fmaxf(*slot, 1e-8f) / 32767.f;
  int i = blockIdx.x * 256 + threadIdx.x;       // < cE * 144
  int r = i / 144, c8 = i - r * 144;
  const float4* p = (const float4*)(w + (long)r * cE + c8 * 8);
  float4 v0 = p[0], v1 = p[1];
  float xv[8] = {v0.x, v0.y, v0.z, v0.w, v1.x, v1.y, v1.z, v1.w};
  ushort_t o[24] __attribute__((aligned(16)));
#pragma unroll
  for (int j = 0; j < 8; ++j) {
    float t = rintf(xv[j] / s); t = fminf(fmaxf(t, -32767.f), 32767.f);
    float v = t * s;
    ushort_t h = f2bf(v);
    ushort_t l = f2bf(v - bf2f(h));
    o[j * 3 + 0] = h; o[j * 3 + 1] = l; o[j * 3 + 2] = h;
  }
  ushort_t* dst = W2 + (long)r * cKP + c8 * 24;
  *(uint4*)(dst) = *(const uint4*)(o);
  *(uint4*)(dst + 8) = *(const uint4*)(o + 8);
  *(uint4*)(dst + 16) = *(const uint4*)(o + 16);
}

// ---------------------------------------------------------------------------
// bf16 MFMA GEMM, 128x128 tile, BK=32, double-buffered LDS, 2-phase prefetch.
// OM 0: z in {0,1,2} selects W2/bias/out (Rq/Rk/Rv), layout (bh,S,72),
//       fused absmax into scal slot 5+z.
// OM 1: single plane, fp32 flat (M,E) out.
template <int OM>
__global__ __launch_bounds__(256) void mgemm_k(const ushort_t* __restrict__ A2,
                                               const ushort_t* __restrict__ W2base,
                                               const float* __restrict__ b0, const float* __restrict__ b1,
                                               const float* __restrict__ b2,
                                               float* __restrict__ outbase, unsigned int* __restrict__ amax) {
  __shared__ ushort_t As[2][4096];   // 2 bufs x (128 rows x 32 bf16)
  __shared__ ushort_t Bs[2][4096];
  int z = (OM == 0) ? blockIdx.z : 0;
  const ushort_t* W2 = W2base + (size_t)z * cE * cKP;
  const float* bias = (z == 0) ? b0 : (z == 1) ? b1 : b2;
  float* out = outbase + (long)z * cQKV;

  int tid = threadIdx.x, w = tid >> 6, lane = tid & 63;
  int lr = lane & 15, kc = lane >> 4;
  int mt = blockIdx.y * 128, nt = blockIdx.x * 128;
  int wr = (w >> 1) * 64, wc = (w & 1) * 64;

  // staging map: phase p LDS byte = p*4096 + w*1024 + lane*16 (within 8KB half)
  int sb0 = w * 1024 + lane * 16;
  int row0 = sb0 >> 6, c0 = (((sb0 >> 4) & 3) - (row0 >> 1)) & 3;
  int sb1 = 4096 + w * 1024 + lane * 16;
  int row1 = sb1 >> 6, c1 = (((sb1 >> 4) & 3) - (row1 >> 1)) & 3;
  const ushort_t* Ag0 = A2 + (long)(mt + row0) * cKP + c0 * 8;
  const ushort_t* Ag1 = A2 + (long)(mt + row1) * cKP + c1 * 8;
  const ushort_t* Bg0 = W2 + (long)(nt + row0) * cKP + c0 * 8;
  const ushort_t* Bg1 = W2 + (long)(nt + row1) * cKP + c1 * 8;

  // ds_read offsets (ushort units), constant over K
  int aoff[4], boff[4];
#pragma unroll
  for (int i = 0; i < 4; ++i) {
    int ar = wr + i * 16 + lr;
    aoff[i] = ar * 32 + (((kc + (ar >> 1)) & 3) * 8);
    int br = wc + i * 16 + lr;
    boff[i] = br * 32 + (((kc + (br >> 1)) & 3) * 8);
  }

#define STAGE(buf, kk)                                          \
  do {                                                          \
    gload16(Ag0 + (long)(kk) * 32, &As[buf][w * 512]);          \
    gload16(Ag1 + (long)(kk) * 32, &As[buf][2048 + w * 512]);   \
    gload16(Bg0 + (long)(kk) * 32, &Bs[buf][w * 512]);          \
    gload16(Bg1 + (long)(kk) * 32, &Bs[buf][2048 + w * 512]);   \
  } while (0)

  f32x4 acc[4][4] = {};
  STAGE(0, 0);
  __syncthreads();
  int cur = 0;
  for (int kk = 0; kk < cKP / 32; ++kk) {
    if (kk < cKP / 32 - 1) STAGE(cur ^ 1, kk + 1);
    bf16x8 af[4], bfr[4];
#pragma unroll
    for (int i = 0; i < 4; ++i) af[i] = *(const bf16x8*)&As[cur][aoff[i]];
#pragma unroll
    for (int j = 0; j < 4; ++j) bfr[j] = *(const bf16x8*)&Bs[cur][boff[j]];
#pragma unroll
    for (int i = 0; i < 4; ++i)
#pragma unroll
      for (int j = 0; j < 4; ++j)
        acc[i][j] = MFMA16(af[i], bfr[j], acc[i][j], 0, 0, 0);
    __syncthreads();     // drains vmcnt+lgkmcnt: next buf ready, cur reusable
    cur ^= 1;
  }
#undef STAGE

  // epilogue: C row = mt + wr + i*16 + kc*4 + r, col = nt + wc + j*16 + lr
  float amx = 0.f;
#pragma unroll
  for (int i = 0; i < 4; ++i) {
#pragma unroll
    for (int r = 0; r < 4; ++r) {
      int m = mt + wr + i * 16 + kc * 4 + r;
      if (m >= cM) continue;
      int b = m / cS, s = m - b * cS;
#pragma unroll
      for (int j = 0; j < 4; ++j) {
        int n = nt + wc + j * 16 + lr;
        float cv = acc[i][j][r] + bias[n];
        if (OM == 1) {
          out[(long)m * cE + n] = cv;
        } else {
          int h = n / cD, d = n - h * cD;
          out[((long)(b * cH + h) * cS + s) * cD + d] = cv;
          amx = fmaxf(amx, fabsf(cv));
        }
      }
    }
  }
  if (OM == 0) {
    for (int o = 32; o; o >>= 1) amx = fmaxf(amx, __shfl_xor(amx, o));
    if (lane == 0) atomicMax(&amax[5 + z], __float_as_uint(amx));
  }
}

// ---------------------------------------------------------------------------
// q/k fp32 (bh,729,72) -> 8-bit integer as bf16 (bh,768,96), zero pad
__global__ __launch_bounds__(256) void qk8_k(const float* __restrict__ src, ushort_t* __restrict__ dst,
                                             const float* __restrict__ slot) {
  float s8 = fmaxf(*slot, 1e-8f) / 127.f;
  long total2 = (long)256 * cSP * cDP96 / 2;
  long i = (long)blockIdx.x * blockDim.x + threadIdx.x;
  long str = (long)gridDim.x * blockDim.x;
  for (; i < total2; i += str) {
    long e = i * 2;
    int d = (int)(e % cDP96);
    long rem = e / cDP96;
    int s = (int)(rem % cSP);
    int bh = (int)(rem / cSP);
    float v0 = 0.f, v1 = 0.f;
    if (s < cS && d < cD) {
      const float* p = src + ((long)bh * cS + s) * cD + d;
      v0 = p[0]; v1 = p[1];
    }
    float n0 = fminf(fmaxf(rintf(v0 / s8), -127.f), 127.f);
    float n1 = fminf(fmaxf(rintf(v1 / s8), -127.f), 127.f);
    ushort2 o; o.x = f2bf(n0); o.y = f2bf(n1);
    *(ushort2*)(dst + e) = o;
  }
}

// v fp32 (bh,729,72) -> transposed 8-bit integer bf16 vT (bh,80,768)
__global__ __launch_bounds__(256) void v8T_k(const float* __restrict__ vf, ushort_t* __restrict__ vT,
                                             const float* __restrict__ slot) {
  __shared__ float T[64][73];
  int bh = blockIdx.x, k0 = blockIdx.y * 64;
  int tid = threadIdx.x;
  float s8 = fmaxf(*slot, 1e-8f) / 127.f;
  for (int e = tid; e < 64 * 72; e += 256) {
    int r = e / 72, c = e - r * 72;
    T[r][c] = (k0 + r < cS) ? vf[((long)bh * cS + k0 + r) * cD + c] : 0.f;
  }
  __syncthreads();
  for (int e = tid; e < 64 * 80; e += 256) {
    int d = e >> 6, kk = e & 63;
    float val = (d < cD && k0 + kk < cS) ? T[kk][d] : 0.f;
    float n = fminf(fmaxf(rintf(val / s8), -127.f), 127.f);
    vT[((long)bh * cVD + d) * cSP + k0 + kk] = f2bf(n);
  }
}

// ---------------------------------------------------------------------------
// pass A: swapped mfma(K,Q) -> per-row m,Z; global min Z.  grid (12, 256)
__global__ __launch_bounds__(256) void qk_statsA(const ushort_t* __restrict__ qb,
                                                 const ushort_t* __restrict__ kb,
                                                 const float* __restrict__ scal,
                                                 float* __restrict__ rowM, float* __restrict__ rowZ,
                                                 unsigned int* __restrict__ minZ) {
  int bh = blockIdx.y;
  int w = threadIdx.x >> 6, lane = threadIdx.x & 63;
  int lr = lane & 15, lg = lane >> 4;
  int q0 = blockIdx.x * 64 + w * 16;
  float f = (fmaxf(scal[5], 1e-8f) / 127.f) * (fmaxf(scal[6], 1e-8f) / 127.f) * cScale;
  const ushort_t* Qp = qb + ((long)bh * cSP + q0 + lr) * cDP96 + lg * 8;
  bf16x8 qa0 = *(const bf16x8*)(Qp);
  bf16x8 qa1 = *(const bf16x8*)(Qp + 32);
  bf16x8 qa2 = *(const bf16x8*)(Qp + 64);
  const ushort_t* Kp0 = kb + ((long)bh * cSP + lr) * cDP96 + lg * 8;
  float m = -INFINITY, z = 0.f;
  for (int k0 = 0; k0 < 736; k0 += 16) {
    const ushort_t* Kp = Kp0 + (long)k0 * cDP96;
    f32x4 acc = {0.f, 0.f, 0.f, 0.f};
    acc = MFMA16(*(const bf16x8*)(Kp),      qa0, acc, 0, 0, 0);
    acc = MFMA16(*(const bf16x8*)(Kp + 32), qa1, acc, 0, 0, 0);
    acc = MFMA16(*(const bf16x8*)(Kp + 64), qa2, acc, 0, 0, 0);
    int kbase = k0 + lg * 4;
    float l0 = (kbase + 0 < cS) ? acc[0] * f : -INFINITY;
    float l1 = (kbase + 1 < cS) ? acc[1] * f : -INFINITY;
    float l2 = (kbase + 2 < cS) ? acc[2] * f : -INFINITY;
    float l3 = (kbase + 3 < cS) ? acc[3] * f : -INFINITY;
    float tm = fmaxf(fmaxf(l0, l1), fmaxf(l2, l3));
    float mn = fmaxf(m, tm);
    z = z * __expf(m - mn) + __expf(l0 - mn) + __expf(l1 - mn) + __expf(l2 - mn) + __expf(l3 - mn);
    m = mn;
  }
#pragma unroll
  for (int o = 16; o <= 32; o <<= 1) {
    float mo = __shfl_xor(m, o);
    float zo = __shfl_xor(z, o);
    float mn = fmaxf(m, mo);
    z = z * __expf(m - mn) + zo * __expf(mo - mn);
    m = mn;
  }
  int q = q0 + lr;
  if (lane < 16 && q < cS) {
    rowM[(long)bh * cS + q] = m;
    rowZ[(long)bh * cS + q] = z;
  }
  float zs = (q < cS) ? z : __uint_as_float(0x7f800000u);
#pragma unroll
  for (int o = 1; o < 16; o <<= 1) zs = fminf(zs, __shfl_xor(zs, o));
  if (lane == 0) atomicMin(minZ, __float_as_uint(zs));
}

// ---------------------------------------------------------------------------
// pass B fused, wave-independent (no block barriers): P = fq16(softmax) -> P,
// attn = P @ v * sv -> attn, fused absmax(attn) -> scal[9].  grid (12, 256)
__global__ __launch_bounds__(256) void qk_pv(const ushort_t* __restrict__ qb,
                                             const ushort_t* __restrict__ kb,
                                             const ushort_t* __restrict__ vT,
                                             const float* __restrict__ rowM, const float* __restrict__ rowZ,
                                             float* __restrict__ scal,
                                             float* __restrict__ P, float* __restrict__ attn) {
  __shared__ float Pt[4][16][68];   // per-wave slice
  int qt = blockIdx.x, bh = blockIdx.y;
  int tid = threadIdx.x, w = tid >> 6, lane = tid & 63;
  int lr = lane & 15, lg = lane >> 4;
  int qw = qt * 64 + w * 16;
  float f = (fmaxf(scal[5], 1e-8f) / 127.f) * (fmaxf(scal[6], 1e-8f) / 127.f) * cScale;
  float sv = fmaxf(scal[7], 1e-8f) / 127.f;
  float sp = fmaxf(1.0f / scal[8], 1e-8f) / 32767.f;
  float mr[4], cr[4];
#pragma unroll
  for (int r = 0; r < 4; ++r) {
    int qq = qw + lg * 4 + r;
    bool v = qq < cS;
    mr[r] = v ? rowM[(long)bh * cS + qq] : 0.f;
    float Z = v ? rowZ[(long)bh * cS + qq] : 1.f;
    cr[r] = v ? 1.0f / (Z * sp) : 0.f;
  }
  const ushort_t* Qp = qb + ((long)bh * cSP + qw + lr) * cDP96 + lg * 8;
  bf16x8 qa0 = *(const bf16x8*)(Qp);
  bf16x8 qa1 = *(const bf16x8*)(Qp + 32);
  bf16x8 qa2 = *(const bf16x8*)(Qp + 64);
  f32x4 accPV[5] = {};
  for (int c = 0; c < 12; ++c) {
    int k0 = c * 64;
    // ---- QK: 4 n-tiles of 16 k -> quantized probs into this wave's Pt slice
#pragma unroll
    for (int t = 0; t < 4; ++t) {
      const ushort_t* Kp = kb + ((long)bh * cSP + k0 + t * 16 + lr) * cDP96 + lg * 8;
      f32x4 acc = {0.f, 0.f, 0.f, 0.f};
      acc = MFMA16(qa0, *(const bf16x8*)(Kp),      acc, 0, 0, 0);
      acc = MFMA16(qa1, *(const bf16x8*)(Kp + 32), acc, 0, 0, 0);
      acc = MFMA16(qa2, *(const bf16x8*)(Kp + 64), acc, 0, 0, 0);
      bool kval = (k0 + t * 16 + lr) < cS;
#pragma unroll
      for (int r = 0; r < 4; ++r) {
        float e = __expf(acc[r] * f - mr[r]);
        float n = rintf(e * cr[r]);
        n = fminf(n, 32767.f);
        Pt[w][lg * 4 + r][t * 16 + lr] = kval ? n * sp : 0.f;
      }
    }
    __builtin_amdgcn_wave_barrier();  // compiler fence (wave-synchronous LDS)
    // ---- V frag prefetch (in flight during P write)
    bf16x8 vfr[2][5];
#pragma unroll
    for (int ks = 0; ks < 2; ++ks)
#pragma unroll
      for (int dt = 0; dt < 5; ++dt)
        vfr[ks][dt] = *(const bf16x8*)(vT + ((long)bh * cVD + dt * 16 + lr) * cSP + k0 + ks * 32 + lg * 8);
    // ---- coalesced P write: 16 rows x 64 cols, one 256B row per iter
    int ncol = cS - k0; if (ncol > 64) ncol = 64;
#pragma unroll 4
    for (int j = 0; j < 16; ++j) {
      int q = qw + j;
      if (q < cS && lane < ncol)
        P[((long)bh * cS + q) * cS + k0 + lane] = Pt[w][j][lane];
    }
    __builtin_amdgcn_wave_barrier();
    // ---- PV: A = P rows (Dekker hi/lo bf16), B = vT
#pragma unroll
    for (int ks = 0; ks < 2; ++ks) {
      const float* prow = &Pt[w][lr][ks * 32 + lg * 8];
      bf16x8 hif, lof;
#pragma unroll
      for (int i = 0; i < 8; ++i) {
        float p = prow[i];
        unsigned short hu = f2bf(p);
        float lo = p - bf2f(hu);
        hif[i] = (short)hu;
        lof[i] = (short)f2bf(lo);
      }
#pragma unroll
      for (int dt = 0; dt < 5; ++dt) {
        accPV[dt] = MFMA16(hif, vfr[ks][dt], accPV[dt], 0, 0, 0);
        accPV[dt] = MFMA16(lof, vfr[ks][dt], accPV[dt], 0, 0, 0);
      }
    }
    __builtin_amdgcn_wave_barrier();
  }
  // epilogue: attn (B,S,E) fp32 + fused absmax -> scal[9]
  int b = bh >> 4, h = bh & 15;
  float amx = 0.f;
#pragma unroll
  for (int dt = 0; dt < 5; ++dt) {
#pragma unroll
    for (int r = 0; r < 4; ++r) {
      int q = qw + lg * 4 + r, d = dt * 16 + lr;
      if (q < cS && d < cD) {
        float av = accPV[dt][r] * sv;
        attn[((long)(b * cS + q)) * cE + h * cD + d] = av;
        amx = fmaxf(amx, fabsf(av));
      }
    }
  }
  for (int o = 32; o; o >>= 1) amx = fmaxf(amx, __shfl_xor(amx, o));
  if (lane == 0) atomicMax((unsigned int*)(scal + 9), __float_as_uint(amx));
}

// ---------------------------------------------------------------------------
extern "C" void kernel_launch(void* const* d_in, const int* in_sizes, int n_in,
                              void* d_out, int out_size, void* d_ws, size_t ws_size,
                              hipStream_t stream) {
  (void)in_sizes; (void)n_in; (void)out_size;
  if (ws_size < WS_TOTAL) return;

  const float* hs = (const float*)d_in[0];
  const float* wq = (const float*)d_in[1];
  const float* bq = (const float*)d_in[2];
  const float* wk = (const float*)d_in[3];
  const float* bk = (const float*)d_in[4];
  const float* wv = (const float*)d_in[5];
  const float* bv = (const float*)d_in[6];
  const float* wo = (const float*)d_in[7];
  const float* bo = (const float*)d_in[8];

  char* ws = (char*)d_ws;
  float* scal = (float*)(ws + B_SCAL);
  ushort_t* W2O  = (ushort_t*)(ws + B_W2O);
  ushort_t* W2Q  = (ushort_t*)(ws + B_W2Q);   // W2K, W2V follow contiguously
  ushort_t* A2   = (ushort_t*)(ws + B_A2);
  ushort_t* vT   = (ushort_t*)(ws + B_VT);
  ushort_t* qb   = (ushort_t*)(ws + B_QB);
  ushort_t* kb   = (ushort_t*)(ws + B_KB);
  float* rowM = (float*)(ws + B_ROWM);
  float* rowZ = (float*)(ws + B_ROWZ);

  float* outb = (float*)d_out;           // attn_output region (also attn scratch)
  float* Pout = outb + cQKV;             // attn_weights region (also Rq/Rk/Rv scratch)
  float* Rq = Pout;                      // fp32 q (bh,S,72)
  float* Rk = Pout + cQKV;
  float* Rv = Pout + 2 * cQKV;

  init_k<<<1, 64, 0, stream>>>(scal);

  // absmax of raw inputs
  absmax_k<<<1024, 256, 0, stream>>>((const float4*)hs, cQKV / 4, (unsigned int*)(scal + 0));
  absmax_k<<<512, 256, 0, stream>>>((const float4*)wq, cWN / 4, (unsigned int*)(scal + 1));
  absmax_k<<<512, 256, 0, stream>>>((const float4*)wk, cWN / 4, (unsigned int*)(scal + 2));
  absmax_k<<<512, 256, 0, stream>>>((const float4*)wv, cWN / 4, (unsigned int*)(scal + 3));
  absmax_k<<<512, 256, 0, stream>>>((const float4*)wo, cWN / 4, (unsigned int*)(scal + 4));

  // pack weights + hidden (once)
  packW_k<<<648, 256, 0, stream>>>(wq, scal + 1, W2Q);
  packW_k<<<648, 256, 0, stream>>>(wk, scal + 2, W2Q + (size_t)cE * cKP);
  packW_k<<<648, 256, 0, stream>>>(wv, scal + 3, W2Q + 2 * (size_t)cE * cKP);
  packW_k<<<648, 256, 0, stream>>>(wo, scal + 4, W2O);
  packA_k<<<6624, 256, 0, stream>>>(hs, scal + 0, A2);

  // merged Q/K/V projection (fused absmax -> slots 5,6,7)
  mgemm_k<0><<<dim3(9, 92, 3), 256, 0, stream>>>(A2, W2Q, bq, bk, bv, Rq, (unsigned int*)scal);

  // 8-bit integer-bf16 conversions
  qk8_k<<<4096, 256, 0, stream>>>(Rq, qb, scal + 5);
  qk8_k<<<4096, 256, 0, stream>>>(Rk, kb, scal + 6);
  v8T_k<<<dim3(256, 12), 256, 0, stream>>>(Rv, vT, scal + 7);

  // attention
  qk_statsA<<<dim3(12, 256), 256, 0, stream>>>(qb, kb, scal, rowM, rowZ, (unsigned int*)(scal + 8));
  qk_pv<<<dim3(12, 256), 256, 0, stream>>>(qb, kb, vT, rowM, rowZ, scal, Pout, outb);

  // O projection: pack attn (slot 9 from qk_pv), GEMM -> final attn_output
  packA_k<<<6624, 256, 0, stream>>>(outb, scal + 9, A2);
  mgemm_k<1><<<dim3(9, 92, 1), 256, 0, stream>>>(A2, W2O, bo, bo, bo, outb, nullptr);
}

// Round 6
// 1045.178 us; speedup vs baseline: 5.7547x; 1.4582x over previous
//
#include <hip/hip_runtime.h>
#include <cstdint>
#include <cstddef>

// ---------------------------------------------------------------------------
// SiglipAttention fake-quant.  B=16 S=729 E=1152 H=16 D=72.
// Outputs fp32: attn_output (B,S,E) then attn_weights (B,H,S,S).
// Round 6: projections via EXACT int8 MFMA (hi/lo byte split of fq16 ints),
//          i32 accumulators, fp32 combine; 3x less operand traffic.
// ---------------------------------------------------------------------------

typedef unsigned short ushort_t;

constexpr int   cB = 16, cS = 729, cE = 1152, cH = 16, cD = 72;
constexpr int   cM = cB * cS;                    // 11664
constexpr long  cQKV  = (long)cM * cE;           // 13,436,928
constexpr long  cWN   = (long)cE * cE;           // 1,327,104
constexpr float cScale = 0.11785113019775792f;   // 72^-0.5
constexpr int   cSP = 768;                       // padded S rows for qb/kb
constexpr int   cDP96 = 96;                      // padded D for MFMA K
constexpr int   cVD = 80;                        // vT d-rows (72 used + 8 pad)
constexpr int   cMF = 11776;                     // padded M (92 tiles of 128)
constexpr int   cRB = 2304;                      // i8 row bytes: [h 1152 | l 1152]

// ---- workspace byte offsets (total ~147 MB <= proven 243.7 MB) -------------
constexpr size_t B_SCAL = 0;                                    // 16 f32
constexpr size_t SZ_W2  = (size_t)cE * cRB;                     // 2,654,208
constexpr size_t B_W2O  = 256;
constexpr size_t B_W2Q  = B_W2O + SZ_W2;                        // W2Q,K,V contiguous
constexpr size_t B_A2   = B_W2Q + 3 * SZ_W2;
constexpr size_t SZ_A2  = (size_t)cMF * cRB;                    // 27,131,904
constexpr size_t B_VT   = B_A2 + SZ_A2;
constexpr size_t SZ_VT  = (size_t)256 * cVD * cSP * 2;          // 31,457,280
constexpr size_t B_QB   = B_VT + SZ_VT;
constexpr size_t SZ_QB  = (size_t)256 * cSP * cDP96 * 2;        // 37,748,736
constexpr size_t B_KB   = B_QB + SZ_QB;
constexpr size_t B_ROWM = B_KB + SZ_QB;
constexpr size_t SZ_ROW = (size_t)256 * cS * 4;                 // 746,496
constexpr size_t B_ROWZ = B_ROWM + SZ_ROW;
constexpr size_t WS_TOTAL = B_ROWZ + SZ_ROW;
static_assert(WS_TOTAL <= 243689728, "stay under proven ws size");

// scalar slots: 0 hid,1 wq,2 wk,3 wv,4 wo,5 q,6 k,7 v,8 minZ,9 attn

typedef __attribute__((ext_vector_type(8))) short bf16x8;
typedef __attribute__((ext_vector_type(4))) float f32x4;
typedef __attribute__((ext_vector_type(4))) int   i32x4;
#define MFMA16 __builtin_amdgcn_mfma_f32_16x16x32_bf16
#define MFMAI8 __builtin_amdgcn_mfma_i32_16x16x64_i8

__device__ __forceinline__ unsigned short f2bf(float f) {
  unsigned u = __float_as_uint(f);
  return (unsigned short)((u + 0x7fffu + ((u >> 16) & 1u)) >> 16);   // RNE
}
__device__ __forceinline__ float bf2f(unsigned short h) {
  return __uint_as_float(((unsigned)h) << 16);
}
__device__ __forceinline__ void gload16(const void* g, void* l) {
  __builtin_amdgcn_global_load_lds((const __attribute__((address_space(1))) unsigned int*)g,
                                   (__attribute__((address_space(3))) unsigned int*)l, 16, 0, 0);
}

// ---------------------------------------------------------------------------
__global__ void init_k(float* sc) {
  int t = threadIdx.x;
  if (t < 16) sc[t] = (t == 8) ? __uint_as_float(0x7f800000u) : 0.0f;
}

__global__ __launch_bounds__(256) void absmax_k(const float4* __restrict__ x, long n4,
                                                unsigned int* __restrict__ slot) {
  float m = 0.f;
  long i = (long)blockIdx.x * blockDim.x + threadIdx.x;
  long str = (long)gridDim.x * blockDim.x;
  for (; i < n4; i += str) {
    float4 v = x[i];
    m = fmaxf(m, fmaxf(fmaxf(fabsf(v.x), fabsf(v.y)), fmaxf(fabsf(v.z), fabsf(v.w))));
  }
  for (int o = 32; o; o >>= 1) m = fmaxf(m, __shfl_xor(m, o));
  __shared__ float red[4];
  int lane = threadIdx.x & 63, w = threadIdx.x >> 6;
  if (!lane) red[w] = m;
  __syncthreads();
  if (threadIdx.x == 0) {
    m = red[0];
    for (int j = 1; j < (int)(blockDim.x >> 6); ++j) m = fmaxf(m, red[j]);
    atomicMax(slot, __float_as_uint(m));
  }
}

// ---------------------------------------------------------------------------
// fq16 -> integer n -> hi/lo i8 planes: n = 256*a + b (exact except clamp tail)
// dst row layout: [h bytes 0..1151 | l bytes 0..1151]
__global__ __launch_bounds__(256) void pack8_k(const float* __restrict__ src, const float* __restrict__ slot,
                                               char* __restrict__ dst, int nsrc) {
  float s = fmaxf(*slot, 1e-8f) / 32767.f;
  int i = blockIdx.x * 256 + threadIdx.x;       // r = i/72 < ndst (grid-sized)
  int r = i / 72, c16 = i - r * 72;
  int m = (r < nsrc) ? r : nsrc - 1;
  const float4* p = (const float4*)(src + (long)m * cE + c16 * 16);
  float4 v[4] = {p[0], p[1], p[2], p[3]};
  const float* xv = (const float*)v;
  unsigned char hb[16] __attribute__((aligned(16)));
  unsigned char lb[16] __attribute__((aligned(16)));
#pragma unroll
  for (int j = 0; j < 16; ++j) {
    float t = rintf(xv[j] / s);
    t = fminf(fmaxf(t, -32767.f), 32767.f);
    float af = floorf(t * 0.00390625f + 0.5f);   // round-half-up to hi byte
    af = fminf(af, 127.f);
    float bf = t - 256.f * af;
    bf = fminf(fmaxf(bf, -128.f), 127.f);
    hb[j] = (unsigned char)((int)af & 0xff);
    lb[j] = (unsigned char)((int)bf & 0xff);
  }
  char* d = dst + (long)r * cRB + c16 * 16;
  *(uint4*)d = *(const uint4*)hb;
  *(uint4*)(d + 1152) = *(const uint4*)lb;
}

// ---------------------------------------------------------------------------
// int8 MFMA GEMM: n_a*n_w = 65536*ac + 256*(ad+bc) [+ bd dropped, ~1e-4 rel].
// 128x128 tile, K-step 64, dbuf LDS, chunk-XOR swizzle (2-way conflicts).
// OM 0: z {0,1,2} -> W2/bias/out (Rq/Rk/Rv) layout (bh,S,72), fused absmax.
// OM 1: flat (M,E) out.
template <int OM>
__global__ __launch_bounds__(256, 2) void mgemm_k(const char* __restrict__ A2,
                                                  const char* __restrict__ W2base,
                                                  const float* __restrict__ b0, const float* __restrict__ b1,
                                                  const float* __restrict__ b2,
                                                  float* __restrict__ outbase, float* __restrict__ scal) {
  __shared__ char L[2][32768];   // per buf: A 128x128B at 0, W 128x128B at 16384
  int z = (OM == 0) ? blockIdx.z : 0;
  const char* W2 = W2base + (size_t)z * cE * cRB;
  const float* bias = (z == 0) ? b0 : (z == 1) ? b1 : b2;
  float* out = outbase + (long)z * cQKV;
  float sA = fmaxf(scal[OM == 0 ? 0 : 9], 1e-8f) / 32767.f;
  float sW = fmaxf(scal[OM == 0 ? 1 + z : 4], 1e-8f) / 32767.f;
  float sc = sA * sW;

  int tid = threadIdx.x, w = tid >> 6, lane = tid & 63;
  int lr = lane & 15, kc = lane >> 4;
  int mt = blockIdx.y * 128, nt = blockIdx.x * 128;
  int wr = (w >> 1) * 64, wc = (w & 1) * 64;

  // staging: waves 0-1 fill A region, waves 2-3 fill W region; 8 x 1KB segs each.
  // LDS row = 128 B = 8 chunks of 16 B, stored chunk = orig ^ (row&7).
  bool isA = (w < 2);
  const char* mat = isA ? (A2 + (long)mt * cRB) : (W2 + (long)nt * cRB);
  const char* src[8];
  int ldo[8];
#pragma unroll
  for (int j = 0; j < 8; ++j) {
    int seg = (w & 1) * 8 + j;                    // 0..15 within region
    int o = seg * 1024 + lane * 16;
    int row = o >> 7, chs = (o >> 4) & 7, orig = chs ^ (row & 7);
    src[j] = mat + (long)row * cRB + (orig >> 2) * 1152 + (orig & 3) * 16;
    ldo[j] = (isA ? 0 : 16384) + seg * 1024;
  }

  // ds_read offsets: plane h = chunks 0..3 (chunk kc), plane l = 4..7
  int aoffH[4], aoffL[4], boffH[4], boffL[4];
#pragma unroll
  for (int i = 0; i < 4; ++i) {
    int ra = wr + i * 16 + lr;
    aoffH[i] = ra * 128 + ((kc ^ (ra & 7)) << 4);
    aoffL[i] = ra * 128 + (((kc + 4) ^ (ra & 7)) << 4);
    int rb = wc + i * 16 + lr;
    boffH[i] = 16384 + rb * 128 + ((kc ^ (rb & 7)) << 4);
    boffL[i] = 16384 + rb * 128 + (((kc + 4) ^ (rb & 7)) << 4);
  }

  auto stage = [&](int buf, int kk) {
#pragma unroll
    for (int j = 0; j < 8; ++j)
      gload16(src[j] + (long)kk * 64, &L[buf][ldo[j]]);
  };

  i32x4 P1[4][4] = {};
  i32x4 Pm[4][4] = {};
  stage(0, 0);
  __syncthreads();
  int cur = 0;
  for (int kk = 0; kk < 18; ++kk) {
    if (kk < 17) stage(cur ^ 1, kk + 1);
    i32x4 ah[4], al[4], whf[4], wlf[4];
#pragma unroll
    for (int i = 0; i < 4; ++i) {
      ah[i]  = *(const i32x4*)&L[cur][aoffH[i]];
      al[i]  = *(const i32x4*)&L[cur][aoffL[i]];
      whf[i] = *(const i32x4*)&L[cur][boffH[i]];
      wlf[i] = *(const i32x4*)&L[cur][boffL[i]];
    }
#pragma unroll
    for (int i = 0; i < 4; ++i)
#pragma unroll
      for (int j = 0; j < 4; ++j) {
        P1[i][j] = MFMAI8(ah[i], whf[j], P1[i][j], 0, 0, 0);
        Pm[i][j] = MFMAI8(ah[i], wlf[j], Pm[i][j], 0, 0, 0);
        Pm[i][j] = MFMAI8(al[i], whf[j], Pm[i][j], 0, 0, 0);
      }
    __syncthreads();
    cur ^= 1;
  }

  // epilogue: C row = mt + wr + i*16 + kc*4 + r, col = nt + wc + j*16 + lr
  float amx = 0.f;
#pragma unroll
  for (int i = 0; i < 4; ++i) {
#pragma unroll
    for (int r = 0; r < 4; ++r) {
      int m = mt + wr + i * 16 + kc * 4 + r;
      if (m >= cM) continue;
      int b = m / cS, s = m - b * cS;
#pragma unroll
      for (int j = 0; j < 4; ++j) {
        int n = nt + wc + j * 16 + lr;
        float val = 65536.f * (float)P1[i][j][r] + 256.f * (float)Pm[i][j][r];
        float cv = sc * val + bias[n];
        if (OM == 1) {
          out[(long)m * cE + n] = cv;
        } else {
          int h = n / cD, d = n - h * cD;
          out[((long)(b * cH + h) * cS + s) * cD + d] = cv;
          amx = fmaxf(amx, fabsf(cv));
        }
      }
    }
  }
  if (OM == 0) {
    for (int o = 32; o; o >>= 1) amx = fmaxf(amx, __shfl_xor(amx, o));
    if (lane == 0) atomicMax((unsigned int*)(scal + 5 + z), __float_as_uint(amx));
  }
}

// ---------------------------------------------------------------------------
// q/k fp32 (bh,729,72) -> 8-bit integer as bf16 (bh,768,96), zero pad
__global__ __launch_bounds__(256) void qk8_k(const float* __restrict__ src, ushort_t* __restrict__ dst,
                                             const float* __restrict__ slot) {
  float s8 = fmaxf(*slot, 1e-8f) / 127.f;
  long total2 = (long)256 * cSP * cDP96 / 2;
  long i = (long)blockIdx.x * blockDim.x + threadIdx.x;
  long str = (long)gridDim.x * blockDim.x;
  for (; i < total2; i += str) {
    long e = i * 2;
    int d = (int)(e % cDP96);
    long rem = e / cDP96;
    int s = (int)(rem % cSP);
    int bh = (int)(rem / cSP);
    float v0 = 0.f, v1 = 0.f;
    if (s < cS && d < cD) {
      const float* p = src + ((long)bh * cS + s) * cD + d;
      v0 = p[0]; v1 = p[1];
    }
    float n0 = fminf(fmaxf(rintf(v0 / s8), -127.f), 127.f);
    float n1 = fminf(fmaxf(rintf(v1 / s8), -127.f), 127.f);
    ushort2 o; o.x = f2bf(n0); o.y = f2bf(n1);
    *(ushort2*)(dst + e) = o;
  }
}

// v fp32 (bh,729,72) -> transposed 8-bit integer bf16 vT (bh,80,768)
__global__ __launch_bounds__(256) void v8T_k(const float* __restrict__ vf, ushort_t* __restrict__ vT,
                                             const float* __restrict__ slot) {
  __shared__ float T[64][73];
  int bh = blockIdx.x, k0 = blockIdx.y * 64;
  int tid = threadIdx.x;
  float s8 = fmaxf(*slot, 1e-8f) / 127.f;
  for (int e = tid; e < 64 * 72; e += 256) {
    int r = e / 72, c = e - r * 72;
    T[r][c] = (k0 + r < cS) ? vf[((long)bh * cS + k0 + r) * cD + c] : 0.f;
  }
  __syncthreads();
  for (int e = tid; e < 64 * 80; e += 256) {
    int d = e >> 6, kk = e & 63;
    float val = (d < cD && k0 + kk < cS) ? T[kk][d] : 0.f;
    float n = fminf(fmaxf(rintf(val / s8), -127.f), 127.f);
    vT[((long)bh * cVD + d) * cSP + k0 + kk] = f2bf(n);
  }
}

// ---------------------------------------------------------------------------
// pass A: swapped mfma(K,Q) -> per-row m,Z; global min Z.  grid (12, 256)
__global__ __launch_bounds__(256) void qk_statsA(const ushort_t* __restrict__ qb,
                                                 const ushort_t* __restrict__ kb,
                                                 const float* __restrict__ scal,
                                                 float* __restrict__ rowM, float* __restrict__ rowZ,
                                                 unsigned int* __restrict__ minZ) {
  int bh = blockIdx.y;
  int w = threadIdx.x >> 6, lane = threadIdx.x & 63;
  int lr = lane & 15, lg = lane >> 4;
  int q0 = blockIdx.x * 64 + w * 16;
  float f = (fmaxf(scal[5], 1e-8f) / 127.f) * (fmaxf(scal[6], 1e-8f) / 127.f) * cScale;
  const ushort_t* Qp = qb + ((long)bh * cSP + q0 + lr) * cDP96 + lg * 8;
  bf16x8 qa0 = *(const bf16x8*)(Qp);
  bf16x8 qa1 = *(const bf16x8*)(Qp + 32);
  bf16x8 qa2 = *(const bf16x8*)(Qp + 64);
  const ushort_t* Kp0 = kb + ((long)bh * cSP + lr) * cDP96 + lg * 8;
  float m = -INFINITY, z = 0.f;
  for (int k0 = 0; k0 < 736; k0 += 16) {
    const ushort_t* Kp = Kp0 + (long)k0 * cDP96;
    f32x4 acc = {0.f, 0.f, 0.f, 0.f};
    acc = MFMA16(*(const bf16x8*)(Kp),      qa0, acc, 0, 0, 0);
    acc = MFMA16(*(const bf16x8*)(Kp + 32), qa1, acc, 0, 0, 0);
    acc = MFMA16(*(const bf16x8*)(Kp + 64), qa2, acc, 0, 0, 0);
    int kbase = k0 + lg * 4;
    float l0 = (kbase + 0 < cS) ? acc[0] * f : -INFINITY;
    float l1 = (kbase + 1 < cS) ? acc[1] * f : -INFINITY;
    float l2 = (kbase + 2 < cS) ? acc[2] * f : -INFINITY;
    float l3 = (kbase + 3 < cS) ? acc[3] * f : -INFINITY;
    float tm = fmaxf(fmaxf(l0, l1), fmaxf(l2, l3));
    float mn = fmaxf(m, tm);
    z = z * __expf(m - mn) + __expf(l0 - mn) + __expf(l1 - mn) + __expf(l2 - mn) + __expf(l3 - mn);
    m = mn;
  }
#pragma unroll
  for (int o = 16; o <= 32; o <<= 1) {
    float mo = __shfl_xor(m, o);
    float zo = __shfl_xor(z, o);
    float mn = fmaxf(m, mo);
    z = z * __expf(m - mn) + zo * __expf(mo - mn);
    m = mn;
  }
  int q = q0 + lr;
  if (lane < 16 && q < cS) {
    rowM[(long)bh * cS + q] = m;
    rowZ[(long)bh * cS + q] = z;
  }
  float zs = (q < cS) ? z : __uint_as_float(0x7f800000u);
#pragma unroll
  for (int o = 1; o < 16; o <<= 1) zs = fminf(zs, __shfl_xor(zs, o));
  if (lane == 0) atomicMin(minZ, __float_as_uint(zs));
}

// ---------------------------------------------------------------------------
// pass B fused, wave-independent: P = fq16(softmax) -> P, attn = P @ v * sv,
// fused absmax(attn) -> scal[9].  grid (12, 256)
__global__ __launch_bounds__(256) void qk_pv(const ushort_t* __restrict__ qb,
                                             const ushort_t* __restrict__ kb,
                                             const ushort_t* __restrict__ vT,
                                             const float* __restrict__ rowM, const float* __restrict__ rowZ,
                                             float* __restrict__ scal,
                                             float* __restrict__ P, float* __restrict__ attn) {
  __shared__ float Pt[4][16][68];   // per-wave slice
  int qt = blockIdx.x, bh = blockIdx.y;
  int tid = threadIdx.x, w = tid >> 6, lane = tid & 63;
  int lr = lane & 15, lg = lane >> 4;
  int qw = qt * 64 + w * 16;
  float f = (fmaxf(scal[5], 1e-8f) / 127.f) * (fmaxf(scal[6], 1e-8f) / 127.f) * cScale;
  float sv = fmaxf(scal[7], 1e-8f) / 127.f;
  float sp = fmaxf(1.0f / scal[8], 1e-8f) / 32767.f;
  float mr[4], cr[4];
#pragma unroll
  for (int r = 0; r < 4; ++r) {
    int qq = qw + lg * 4 + r;
    bool v = qq < cS;
    mr[r] = v ? rowM[(long)bh * cS + qq] : 0.f;
    float Z = v ? rowZ[(long)bh * cS + qq] : 1.f;
    cr[r] = v ? 1.0f / (Z * sp) : 0.f;
  }
  const ushort_t* Qp = qb + ((long)bh * cSP + qw + lr) * cDP96 + lg * 8;
  bf16x8 qa0 = *(const bf16x8*)(Qp);
  bf16x8 qa1 = *(const bf16x8*)(Qp + 32);
  bf16x8 qa2 = *(const bf16x8*)(Qp + 64);
  f32x4 accPV[5] = {};
  for (int c = 0; c < 12; ++c) {
    int k0 = c * 64;
#pragma unroll
    for (int t = 0; t < 4; ++t) {
      const ushort_t* Kp = kb + ((long)bh * cSP + k0 + t * 16 + lr) * cDP96 + lg * 8;
      f32x4 acc = {0.f, 0.f, 0.f, 0.f};
      acc = MFMA16(qa0, *(const bf16x8*)(Kp),      acc, 0, 0, 0);
      acc = MFMA16(qa1, *(const bf16x8*)(Kp + 32), acc, 0, 0, 0);
      acc = MFMA16(qa2, *(const bf16x8*)(Kp + 64), acc, 0, 0, 0);
      bool kval = (k0 + t * 16 + lr) < cS;
#pragma unroll
      for (int r = 0; r < 4; ++r) {
        float e = __expf(acc[r] * f - mr[r]);
        float n = rintf(e * cr[r]);
        n = fminf(n, 32767.f);
        Pt[w][lg * 4 + r][t * 16 + lr] = kval ? n * sp : 0.f;
      }
    }
    __builtin_amdgcn_wave_barrier();
    bf16x8 vfr[2][5];
#pragma unroll
    for (int ks = 0; ks < 2; ++ks)
#pragma unroll
      for (int dt = 0; dt < 5; ++dt)
        vfr[ks][dt] = *(const bf16x8*)(vT + ((long)bh * cVD + dt * 16 + lr) * cSP + k0 + ks * 32 + lg * 8);
    int ncol = cS - k0; if (ncol > 64) ncol = 64;
#pragma unroll 4
    for (int j = 0; j < 16; ++j) {
      int q = qw + j;
      if (q < cS && lane < ncol)
        P[((long)bh * cS + q) * cS + k0 + lane] = Pt[w][j][lane];
    }
    __builtin_amdgcn_wave_barrier();
#pragma unroll
    for (int ks = 0; ks < 2; ++ks) {
      const float* prow = &Pt[w][lr][ks * 32 + lg * 8];
      bf16x8 hif, lof;
#pragma unroll
      for (int i = 0; i < 8; ++i) {
        float p = prow[i];
        unsigned short hu = f2bf(p);
        float lo = p - bf2f(hu);
        hif[i] = (short)hu;
        lof[i] = (short)f2bf(lo);
      }
#pragma unroll
      for (int dt = 0; dt < 5; ++dt) {
        accPV[dt] = MFMA16(hif, vfr[ks][dt], accPV[dt], 0, 0, 0);
        accPV[dt] = MFMA16(lof, vfr[ks][dt], accPV[dt], 0, 0, 0);
      }
    }
    __builtin_amdgcn_wave_barrier();
  }
  int b = bh >> 4, h = bh & 15;
  float amx = 0.f;
#pragma unroll
  for (int dt = 0; dt < 5; ++dt) {
#pragma unroll
    for (int r = 0; r < 4; ++r) {
      int q = qw + lg * 4 + r, d = dt * 16 + lr;
      if (q < cS && d < cD) {
        float av = accPV[dt][r] * sv;
        attn[((long)(b * cS + q)) * cE + h * cD + d] = av;
        amx = fmaxf(amx, fabsf(av));
      }
    }
  }
  for (int o = 32; o; o >>= 1) amx = fmaxf(amx, __shfl_xor(amx, o));
  if (lane == 0) atomicMax((unsigned int*)(scal + 9), __float_as_uint(amx));
}

// ---------------------------------------------------------------------------
extern "C" void kernel_launch(void* const* d_in, const int* in_sizes, int n_in,
                              void* d_out, int out_size, void* d_ws, size_t ws_size,
                              hipStream_t stream) {
  (void)in_sizes; (void)n_in; (void)out_size;
  if (ws_size < WS_TOTAL) return;

  const float* hs = (const float*)d_in[0];
  const float* wq = (const float*)d_in[1];
  const float* bq = (const float*)d_in[2];
  const float* wk = (const float*)d_in[3];
  const float* bk = (const float*)d_in[4];
  const float* wv = (const float*)d_in[5];
  const float* bv = (const float*)d_in[6];
  const float* wo = (const float*)d_in[7];
  const float* bo = (const float*)d_in[8];

  char* ws = (char*)d_ws;
  float* scal = (float*)(ws + B_SCAL);
  char* W2O  = ws + B_W2O;
  char* W2Q  = ws + B_W2Q;    // W2K, W2V follow contiguously
  char* A2   = ws + B_A2;
  ushort_t* vT = (ushort_t*)(ws + B_VT);
  ushort_t* qb = (ushort_t*)(ws + B_QB);
  ushort_t* kb = (ushort_t*)(ws + B_KB);
  float* rowM = (float*)(ws + B_ROWM);
  float* rowZ = (float*)(ws + B_ROWZ);

  float* outb = (float*)d_out;           // attn_output region (also attn scratch)
  float* Pout = outb + cQKV;             // attn_weights region (also Rq/Rk/Rv scratch)
  float* Rq = Pout;
  float* Rk = Pout + cQKV;
  float* Rv = Pout + 2 * cQKV;

  init_k<<<1, 64, 0, stream>>>(scal);

  // absmax of raw inputs
  absmax_k<<<1024, 256, 0, stream>>>((const float4*)hs, cQKV / 4, (unsigned int*)(scal + 0));
  absmax_k<<<512, 256, 0, stream>>>((const float4*)wq, cWN / 4, (unsigned int*)(scal + 1));
  absmax_k<<<512, 256, 0, stream>>>((const float4*)wk, cWN / 4, (unsigned int*)(scal + 2));
  absmax_k<<<512, 256, 0, stream>>>((const float4*)wv, cWN / 4, (unsigned int*)(scal + 3));
  absmax_k<<<512, 256, 0, stream>>>((const float4*)wo, cWN / 4, (unsigned int*)(scal + 4));

  // pack weights + hidden to i8 hi/lo planes
  pack8_k<<<324, 256, 0, stream>>>(wq, scal + 1, W2Q, cE);
  pack8_k<<<324, 256, 0, stream>>>(wk, scal + 2, W2Q + SZ_W2, cE);
  pack8_k<<<324, 256, 0, stream>>>(wv, scal + 3, W2Q + 2 * SZ_W2, cE);
  pack8_k<<<324, 256, 0, stream>>>(wo, scal + 4, W2O, cE);
  pack8_k<<<3312, 256, 0, stream>>>(hs, scal + 0, A2, cM);

  // merged Q/K/V projection (fused absmax -> slots 5,6,7)
  mgemm_k<0><<<dim3(9, 92, 3), 256, 0, stream>>>(A2, W2Q, bq, bk, bv, Rq, scal);

  // 8-bit integer-bf16 conversions for attention
  qk8_k<<<4096, 256, 0, stream>>>(Rq, qb, scal + 5);
  qk8_k<<<4096, 256, 0, stream>>>(Rk, kb, scal + 6);
  v8T_k<<<dim3(256, 12), 256, 0, stream>>>(Rv, vT, scal + 7);

  // attention
  qk_statsA<<<dim3(12, 256), 256, 0, stream>>>(qb, kb, scal, rowM, rowZ, (unsigned int*)(scal + 8));
  qk_pv<<<dim3(12, 256), 256, 0, stream>>>(qb, kb, vT, rowM, rowZ, scal, Pout, outb);

  // O projection: pack attn (slot 9 from qk_pv), GEMM -> final attn_output
  pack8_k<<<3312, 256, 0, stream>>>(outb, scal + 9, A2, cM);
  mgemm_k<1><<<dim3(9, 92, 1), 256, 0, stream>>>(A2, W2O, bo, bo, bo, outb, scal);
}

// Round 8
// 949.766 us; speedup vs baseline: 6.3328x; 1.1005x over previous
//
#include <hip/hip_runtime.h>
#include <cstdint>
#include <cstddef>

// ---------------------------------------------------------------------------
// SiglipAttention fake-quant.  B=16 S=729 E=1152 H=16 D=72.
// Outputs fp32: attn_output (B,S,E) then attn_weights (B,H,S,S).
// Round 7b: fix nontemporal builtin type (ext_vector f32x4, not HIP float4).
// ---------------------------------------------------------------------------

typedef unsigned short ushort_t;

constexpr int   cB = 16, cS = 729, cE = 1152, cH = 16, cD = 72;
constexpr int   cM = cB * cS;                    // 11664
constexpr long  cQKV  = (long)cM * cE;           // 13,436,928
constexpr long  cWN   = (long)cE * cE;           // 1,327,104
constexpr float cScale = 0.11785113019775792f;   // 72^-0.5
constexpr int   cSP = 768;                       // padded S rows for qb/kb
constexpr int   cDP96 = 96;                      // padded D for MFMA K
constexpr int   cVD = 80;                        // vT d-rows (72 used + 8 pad)
constexpr int   cMF = 11776;                     // padded M (92 tiles of 128)
constexpr int   cRB = 2304;                      // i8 row bytes: [h 1152 | l 1152]

// ---- workspace byte offsets (total ~147 MB <= proven 243.7 MB) -------------
constexpr size_t B_SCAL = 0;                                    // 16 f32
constexpr size_t SZ_W2  = (size_t)cE * cRB;                     // 2,654,208
constexpr size_t B_W2O  = 256;
constexpr size_t B_W2Q  = B_W2O + SZ_W2;                        // W2Q,K,V contiguous
constexpr size_t B_A2   = B_W2Q + 3 * SZ_W2;
constexpr size_t SZ_A2  = (size_t)cMF * cRB;                    // 27,131,904
constexpr size_t B_VT   = B_A2 + SZ_A2;
constexpr size_t SZ_VT  = (size_t)256 * cVD * cSP * 2;          // 31,457,280
constexpr size_t B_QB   = B_VT + SZ_VT;
constexpr size_t SZ_QB  = (size_t)256 * cSP * cDP96 * 2;        // 37,748,736
constexpr size_t B_KB   = B_QB + SZ_QB;
constexpr size_t B_ROWM = B_KB + SZ_QB;
constexpr size_t SZ_ROW = (size_t)256 * cS * 4;                 // 746,496
constexpr size_t B_ROWZ = B_ROWM + SZ_ROW;
constexpr size_t WS_TOTAL = B_ROWZ + SZ_ROW;
static_assert(WS_TOTAL <= 243689728, "stay under proven ws size");

// scalar slots: 0 hid,1 wq,2 wk,3 wv,4 wo,5 q,6 k,7 v,8 minZ,9 attn

typedef __attribute__((ext_vector_type(8))) short bf16x8;
typedef __attribute__((ext_vector_type(4))) float f32x4;
typedef __attribute__((ext_vector_type(4))) int   i32x4;
#define MFMA16 __builtin_amdgcn_mfma_f32_16x16x32_bf16
#define MFMAI8 __builtin_amdgcn_mfma_i32_16x16x64_i8

__device__ __forceinline__ unsigned short f2bf(float f) {
  unsigned u = __float_as_uint(f);
  return (unsigned short)((u + 0x7fffu + ((u >> 16) & 1u)) >> 16);   // RNE
}
__device__ __forceinline__ float bf2f(unsigned short h) {
  return __uint_as_float(((unsigned)h) << 16);
}
__device__ __forceinline__ void gload16(const void* g, void* l) {
  __builtin_amdgcn_global_load_lds((const __attribute__((address_space(1))) unsigned int*)g,
                                   (__attribute__((address_space(3))) unsigned int*)l, 16, 0, 0);
}

// ---------------------------------------------------------------------------
__global__ void init_k(float* sc) {
  int t = threadIdx.x;
  if (t < 16) sc[t] = (t == 8) ? __uint_as_float(0x7f800000u) : 0.0f;
}

__global__ __launch_bounds__(256) void absmax_k(const float4* __restrict__ x, long n4,
                                                unsigned int* __restrict__ slot) {
  float m = 0.f;
  long i = (long)blockIdx.x * blockDim.x + threadIdx.x;
  long str = (long)gridDim.x * blockDim.x;
  for (; i < n4; i += str) {
    float4 v = x[i];
    m = fmaxf(m, fmaxf(fmaxf(fabsf(v.x), fabsf(v.y)), fmaxf(fabsf(v.z), fabsf(v.w))));
  }
  for (int o = 32; o; o >>= 1) m = fmaxf(m, __shfl_xor(m, o));
  __shared__ float red[4];
  int lane = threadIdx.x & 63, w = threadIdx.x >> 6;
  if (!lane) red[w] = m;
  __syncthreads();
  if (threadIdx.x == 0) {
    m = red[0];
    for (int j = 1; j < (int)(blockDim.x >> 6); ++j) m = fmaxf(m, red[j]);
    atomicMax(slot, __float_as_uint(m));
  }
}

// ---------------------------------------------------------------------------
// fq16 -> integer n -> hi/lo i8 planes: n = 256*a + b (exact except clamp tail)
__global__ __launch_bounds__(256) void pack8_k(const float* __restrict__ src, const float* __restrict__ slot,
                                               char* __restrict__ dst, int nsrc) {
  float s = fmaxf(*slot, 1e-8f) / 32767.f;
  int i = blockIdx.x * 256 + threadIdx.x;
  int r = i / 72, c16 = i - r * 72;
  int m = (r < nsrc) ? r : nsrc - 1;
  const float4* p = (const float4*)(src + (long)m * cE + c16 * 16);
  float4 v[4] = {p[0], p[1], p[2], p[3]};
  const float* xv = (const float*)v;
  unsigned char hb[16] __attribute__((aligned(16)));
  unsigned char lb[16] __attribute__((aligned(16)));
#pragma unroll
  for (int j = 0; j < 16; ++j) {
    float t = rintf(xv[j] / s);
    t = fminf(fmaxf(t, -32767.f), 32767.f);
    float af = floorf(t * 0.00390625f + 0.5f);   // round-half-up to hi byte
    af = fminf(af, 127.f);
    float bf = t - 256.f * af;
    bf = fminf(fmaxf(bf, -128.f), 127.f);
    hb[j] = (unsigned char)((int)af & 0xff);
    lb[j] = (unsigned char)((int)bf & 0xff);
  }
  char* d = dst + (long)r * cRB + c16 * 16;
  *(uint4*)d = *(const uint4*)hb;
  *(uint4*)(d + 1152) = *(const uint4*)lb;
}

// ---------------------------------------------------------------------------
// int8 MFMA GEMM (unchanged, verified).
template <int OM>
__global__ __launch_bounds__(256, 2) void mgemm_k(const char* __restrict__ A2,
                                                  const char* __restrict__ W2base,
                                                  const float* __restrict__ b0, const float* __restrict__ b1,
                                                  const float* __restrict__ b2,
                                                  float* __restrict__ outbase, float* __restrict__ scal) {
  __shared__ char L[2][32768];
  int z = (OM == 0) ? blockIdx.z : 0;
  const char* W2 = W2base + (size_t)z * cE * cRB;
  const float* bias = (z == 0) ? b0 : (z == 1) ? b1 : b2;
  float* out = outbase + (long)z * cQKV;
  float sA = fmaxf(scal[OM == 0 ? 0 : 9], 1e-8f) / 32767.f;
  float sW = fmaxf(scal[OM == 0 ? 1 + z : 4], 1e-8f) / 32767.f;
  float sc = sA * sW;

  int tid = threadIdx.x, w = tid >> 6, lane = tid & 63;
  int lr = lane & 15, kc = lane >> 4;
  int mt = blockIdx.y * 128, nt = blockIdx.x * 128;
  int wr = (w >> 1) * 64, wc = (w & 1) * 64;

  bool isA = (w < 2);
  const char* mat = isA ? (A2 + (long)mt * cRB) : (W2 + (long)nt * cRB);
  const char* src[8];
  int ldo[8];
#pragma unroll
  for (int j = 0; j < 8; ++j) {
    int seg = (w & 1) * 8 + j;
    int o = seg * 1024 + lane * 16;
    int row = o >> 7, chs = (o >> 4) & 7, orig = chs ^ (row & 7);
    src[j] = mat + (long)row * cRB + (orig >> 2) * 1152 + (orig & 3) * 16;
    ldo[j] = (isA ? 0 : 16384) + seg * 1024;
  }

  int aoffH[4], aoffL[4], boffH[4], boffL[4];
#pragma unroll
  for (int i = 0; i < 4; ++i) {
    int ra = wr + i * 16 + lr;
    aoffH[i] = ra * 128 + ((kc ^ (ra & 7)) << 4);
    aoffL[i] = ra * 128 + (((kc + 4) ^ (ra & 7)) << 4);
    int rb = wc + i * 16 + lr;
    boffH[i] = 16384 + rb * 128 + ((kc ^ (rb & 7)) << 4);
    boffL[i] = 16384 + rb * 128 + (((kc + 4) ^ (rb & 7)) << 4);
  }

  auto stage = [&](int buf, int kk) {
#pragma unroll
    for (int j = 0; j < 8; ++j)
      gload16(src[j] + (long)kk * 64, &L[buf][ldo[j]]);
  };

  i32x4 P1[4][4] = {};
  i32x4 Pm[4][4] = {};
  stage(0, 0);
  __syncthreads();
  int cur = 0;
  for (int kk = 0; kk < 18; ++kk) {
    if (kk < 17) stage(cur ^ 1, kk + 1);
    i32x4 ah[4], al[4], whf[4], wlf[4];
#pragma unroll
    for (int i = 0; i < 4; ++i) {
      ah[i]  = *(const i32x4*)&L[cur][aoffH[i]];
      al[i]  = *(const i32x4*)&L[cur][aoffL[i]];
      whf[i] = *(const i32x4*)&L[cur][boffH[i]];
      wlf[i] = *(const i32x4*)&L[cur][boffL[i]];
    }
#pragma unroll
    for (int i = 0; i < 4; ++i)
#pragma unroll
      for (int j = 0; j < 4; ++j) {
        P1[i][j] = MFMAI8(ah[i], whf[j], P1[i][j], 0, 0, 0);
        Pm[i][j] = MFMAI8(ah[i], wlf[j], Pm[i][j], 0, 0, 0);
        Pm[i][j] = MFMAI8(al[i], whf[j], Pm[i][j], 0, 0, 0);
      }
    __syncthreads();
    cur ^= 1;
  }

  float amx = 0.f;
#pragma unroll
  for (int i = 0; i < 4; ++i) {
#pragma unroll
    for (int r = 0; r < 4; ++r) {
      int m = mt + wr + i * 16 + kc * 4 + r;
      if (m >= cM) continue;
      int b = m / cS, s = m - b * cS;
#pragma unroll
      for (int j = 0; j < 4; ++j) {
        int n = nt + wc + j * 16 + lr;
        float val = 65536.f * (float)P1[i][j][r] + 256.f * (float)Pm[i][j][r];
        float cv = sc * val + bias[n];
        if (OM == 1) {
          out[(long)m * cE + n] = cv;
        } else {
          int h = n / cD, d = n - h * cD;
          out[((long)(b * cH + h) * cS + s) * cD + d] = cv;
          amx = fmaxf(amx, fabsf(cv));
        }
      }
    }
  }
  if (OM == 0) {
    for (int o = 32; o; o >>= 1) amx = fmaxf(amx, __shfl_xor(amx, o));
    if (lane == 0) atomicMax((unsigned int*)(scal + 5 + z), __float_as_uint(amx));
  }
}

// ---------------------------------------------------------------------------
// q/k fp32 (bh,729,72) -> 8-bit integer as bf16 (bh,768,96), zero pad
__global__ __launch_bounds__(256) void qk8_k(const float* __restrict__ src, ushort_t* __restrict__ dst,
                                             const float* __restrict__ slot) {
  float s8 = fmaxf(*slot, 1e-8f) / 127.f;
  long total2 = (long)256 * cSP * cDP96 / 2;
  long i = (long)blockIdx.x * blockDim.x + threadIdx.x;
  long str = (long)gridDim.x * blockDim.x;
  for (; i < total2; i += str) {
    long e = i * 2;
    int d = (int)(e % cDP96);
    long rem = e / cDP96;
    int s = (int)(rem % cSP);
    int bh = (int)(rem / cSP);
    float v0 = 0.f, v1 = 0.f;
    if (s < cS && d < cD) {
      const float* p = src + ((long)bh * cS + s) * cD + d;
      v0 = p[0]; v1 = p[1];
    }
    float n0 = fminf(fmaxf(rintf(v0 / s8), -127.f), 127.f);
    float n1 = fminf(fmaxf(rintf(v1 / s8), -127.f), 127.f);
    ushort2 o; o.x = f2bf(n0); o.y = f2bf(n1);
    *(ushort2*)(dst + e) = o;
  }
}

// v fp32 (bh,729,72) -> transposed 8-bit integer bf16 vT (bh,80,768)
__global__ __launch_bounds__(256) void v8T_k(const float* __restrict__ vf, ushort_t* __restrict__ vT,
                                             const float* __restrict__ slot) {
  __shared__ float T[64][73];
  int bh = blockIdx.x, k0 = blockIdx.y * 64;
  int tid = threadIdx.x;
  float s8 = fmaxf(*slot, 1e-8f) / 127.f;
  for (int e = tid; e < 64 * 72; e += 256) {
    int r = e / 72, c = e - r * 72;
    T[r][c] = (k0 + r < cS) ? vf[((long)bh * cS + k0 + r) * cD + c] : 0.f;
  }
  __syncthreads();
  for (int e = tid; e < 64 * 80; e += 256) {
    int d = e >> 6, kk = e & 63;
    float val = (d < cD && k0 + kk < cS) ? T[kk][d] : 0.f;
    float n = fminf(fmaxf(rintf(val / s8), -127.f), 127.f);
    vT[((long)bh * cVD + d) * cSP + k0 + kk] = f2bf(n);
  }
}

// ---------------------------------------------------------------------------
// pass A: swapped mfma(K,Q) -> per-row m,Z; global min Z.  grid (12, 256)
// 2-stream online softmax (independent (m,z) chains, merged at end).
__global__ __launch_bounds__(256) void qk_statsA(const ushort_t* __restrict__ qb,
                                                 const ushort_t* __restrict__ kb,
                                                 const float* __restrict__ scal,
                                                 float* __restrict__ rowM, float* __restrict__ rowZ,
                                                 unsigned int* __restrict__ minZ) {
  int bh = blockIdx.y;
  int w = threadIdx.x >> 6, lane = threadIdx.x & 63;
  int lr = lane & 15, lg = lane >> 4;
  int q0 = blockIdx.x * 64 + w * 16;
  float f = (fmaxf(scal[5], 1e-8f) / 127.f) * (fmaxf(scal[6], 1e-8f) / 127.f) * cScale;
  const ushort_t* Qp = qb + ((long)bh * cSP + q0 + lr) * cDP96 + lg * 8;
  bf16x8 qa0 = *(const bf16x8*)(Qp);
  bf16x8 qa1 = *(const bf16x8*)(Qp + 32);
  bf16x8 qa2 = *(const bf16x8*)(Qp + 64);
  const ushort_t* Kp0 = kb + ((long)bh * cSP + lr) * cDP96 + lg * 8;
  float m0 = -INFINITY, z0 = 0.f, m1 = -INFINITY, z1 = 0.f;
  for (int k0 = 0; k0 < 736; k0 += 32) {
    const ushort_t* KpA = Kp0 + (long)k0 * cDP96;
    const ushort_t* KpB = KpA + 16 * cDP96;
    f32x4 accA = {0.f, 0.f, 0.f, 0.f};
    f32x4 accB = {0.f, 0.f, 0.f, 0.f};
    accA = MFMA16(*(const bf16x8*)(KpA),      qa0, accA, 0, 0, 0);
    accB = MFMA16(*(const bf16x8*)(KpB),      qa0, accB, 0, 0, 0);
    accA = MFMA16(*(const bf16x8*)(KpA + 32), qa1, accA, 0, 0, 0);
    accB = MFMA16(*(const bf16x8*)(KpB + 32), qa1, accB, 0, 0, 0);
    accA = MFMA16(*(const bf16x8*)(KpA + 64), qa2, accA, 0, 0, 0);
    accB = MFMA16(*(const bf16x8*)(KpB + 64), qa2, accB, 0, 0, 0);
    {
      int kbase = k0 + lg * 4;
      float l0 = (kbase + 0 < cS) ? accA[0] * f : -INFINITY;
      float l1 = (kbase + 1 < cS) ? accA[1] * f : -INFINITY;
      float l2 = (kbase + 2 < cS) ? accA[2] * f : -INFINITY;
      float l3 = (kbase + 3 < cS) ? accA[3] * f : -INFINITY;
      float tm = fmaxf(fmaxf(l0, l1), fmaxf(l2, l3));
      float mn = fmaxf(m0, tm);
      z0 = z0 * __expf(m0 - mn) + __expf(l0 - mn) + __expf(l1 - mn) + __expf(l2 - mn) + __expf(l3 - mn);
      m0 = mn;
    }
    {
      int kbase = k0 + 16 + lg * 4;
      float l0 = (kbase + 0 < cS) ? accB[0] * f : -INFINITY;
      float l1 = (kbase + 1 < cS) ? accB[1] * f : -INFINITY;
      float l2 = (kbase + 2 < cS) ? accB[2] * f : -INFINITY;
      float l3 = (kbase + 3 < cS) ? accB[3] * f : -INFINITY;
      float tm = fmaxf(fmaxf(l0, l1), fmaxf(l2, l3));
      float mn = fmaxf(m1, tm);
      z1 = z1 * __expf(m1 - mn) + __expf(l0 - mn) + __expf(l1 - mn) + __expf(l2 - mn) + __expf(l3 - mn);
      m1 = mn;
    }
  }
  // merge the two streams
  float m = fmaxf(m0, m1);
  float z = z0 * __expf(m0 - m) + z1 * __expf(m1 - m);
  // merge the 4 k-groups (same q across lane^16, lane^32)
#pragma unroll
  for (int o = 16; o <= 32; o <<= 1) {
    float mo = __shfl_xor(m, o);
    float zo = __shfl_xor(z, o);
    float mn = fmaxf(m, mo);
    z = z * __expf(m - mn) + zo * __expf(mo - mn);
    m = mn;
  }
  int q = q0 + lr;
  if (lane < 16 && q < cS) {
    rowM[(long)bh * cS + q] = m;
    rowZ[(long)bh * cS + q] = z;
  }
  float zs = (q < cS) ? z : __uint_as_float(0x7f800000u);
#pragma unroll
  for (int o = 1; o < 16; o <<= 1) zs = fminf(zs, __shfl_xor(zs, o));
  if (lane == 0) atomicMin(minZ, __float_as_uint(zs));
}

// ---------------------------------------------------------------------------
// pass B fused, wave-independent: P = fq16(softmax) -> P (nontemporal),
// attn = P @ v * sv, fused absmax(attn) -> scal[9].  grid (12, 256)
// K fragments register-prefetched one chunk ahead.
__global__ __launch_bounds__(256) void qk_pv(const ushort_t* __restrict__ qb,
                                             const ushort_t* __restrict__ kb,
                                             const ushort_t* __restrict__ vT,
                                             const float* __restrict__ rowM, const float* __restrict__ rowZ,
                                             float* __restrict__ scal,
                                             float* __restrict__ P, float* __restrict__ attn) {
  __shared__ float Pt[4][16][68];   // per-wave slice
  int qt = blockIdx.x, bh = blockIdx.y;
  int tid = threadIdx.x, w = tid >> 6, lane = tid & 63;
  int lr = lane & 15, lg = lane >> 4;
  int qw = qt * 64 + w * 16;
  float f = (fmaxf(scal[5], 1e-8f) / 127.f) * (fmaxf(scal[6], 1e-8f) / 127.f) * cScale;
  float sv = fmaxf(scal[7], 1e-8f) / 127.f;
  float sp = fmaxf(1.0f / scal[8], 1e-8f) / 32767.f;
  float mr[4], cr[4];
#pragma unroll
  for (int r = 0; r < 4; ++r) {
    int qq = qw + lg * 4 + r;
    bool v = qq < cS;
    mr[r] = v ? rowM[(long)bh * cS + qq] : 0.f;
    float Z = v ? rowZ[(long)bh * cS + qq] : 1.f;
    cr[r] = v ? 1.0f / (Z * sp) : 0.f;
  }
  const ushort_t* Qp = qb + ((long)bh * cSP + qw + lr) * cDP96 + lg * 8;
  bf16x8 qa0 = *(const bf16x8*)(Qp);
  bf16x8 qa1 = *(const bf16x8*)(Qp + 32);
  bf16x8 qa2 = *(const bf16x8*)(Qp + 64);

  const ushort_t* Kbase = kb + (long)bh * cSP * cDP96 + (long)lr * cDP96 + lg * 8;
#define LOADK(dst, k0_)                                                        \
  do {                                                                         \
    _Pragma("unroll") for (int t = 0; t < 4; ++t)                              \
      _Pragma("unroll") for (int s = 0; s < 3; ++s)                            \
        dst[t * 3 + s] = *(const bf16x8*)(Kbase + ((long)((k0_) + t * 16)) * cDP96 + s * 32); \
  } while (0)

  bf16x8 kf[12], kfN[12];
  LOADK(kf, 0);
  f32x4 accPV[5] = {};
  for (int c = 0; c < 12; ++c) {
    int k0 = c * 64;
    // prefetch next chunk's K frags (retire under exp + P-write + PV)
    if (c < 11) LOADK(kfN, k0 + 64);
    // ---- QK: 4 n-tiles of 16 k -> quantized probs into this wave's Pt slice
#pragma unroll
    for (int t = 0; t < 4; ++t) {
      f32x4 acc = {0.f, 0.f, 0.f, 0.f};
      acc = MFMA16(qa0, kf[t * 3 + 0], acc, 0, 0, 0);
      acc = MFMA16(qa1, kf[t * 3 + 1], acc, 0, 0, 0);
      acc = MFMA16(qa2, kf[t * 3 + 2], acc, 0, 0, 0);
      bool kval = (k0 + t * 16 + lr) < cS;
#pragma unroll
      for (int r = 0; r < 4; ++r) {
        float e = __expf(acc[r] * f - mr[r]);
        float n = rintf(e * cr[r]);
        n = fminf(n, 32767.f);
        Pt[w][lg * 4 + r][t * 16 + lr] = kval ? n * sp : 0.f;
      }
    }
    __builtin_amdgcn_wave_barrier();
    // ---- V frag loads (cover the P store phase)
    bf16x8 vfr[2][5];
#pragma unroll
    for (int ks = 0; ks < 2; ++ks)
#pragma unroll
      for (int dt = 0; dt < 5; ++dt)
        vfr[ks][dt] = *(const bf16x8*)(vT + ((long)bh * cVD + dt * 16 + lr) * cSP + k0 + ks * 32 + lg * 8);
    // ---- P write: nontemporal (P never re-read on device; avoid L2 thrash)
    if (k0 + 64 <= cS) {
      // full chunk: 4 x f32x4 per lane, coalesced 1KB per instruction
#pragma unroll
      for (int it = 0; it < 4; ++it) {
        int e = it * 64 + lane;
        int row = e >> 4, c4 = e & 15;
        int q = qw + row;
        if (q < cS) {
          f32x4 pv4 = *(const f32x4*)&Pt[w][row][c4 * 4];
          __builtin_nontemporal_store(pv4, (f32x4*)&P[((long)bh * cS + q) * cS + k0 + c4 * 4]);
        }
      }
    } else {
      // tail chunk (k0=704, 25 valid cols): scalar guarded stores
      int ncol = cS - k0;
#pragma unroll 4
      for (int j = 0; j < 16; ++j) {
        int q = qw + j;
        if (q < cS && lane < ncol)
          __builtin_nontemporal_store(Pt[w][j][lane], &P[((long)bh * cS + q) * cS + k0 + lane]);
      }
    }
    __builtin_amdgcn_wave_barrier();
    // ---- PV: A = P rows (Dekker hi/lo bf16), B = vT
#pragma unroll
    for (int ks = 0; ks < 2; ++ks) {
      const float* prow = &Pt[w][lr][ks * 32 + lg * 8];
      bf16x8 hif, lof;
#pragma unroll
      for (int i = 0; i < 8; ++i) {
        float p = prow[i];
        unsigned short hu = f2bf(p);
        float lo = p - bf2f(hu);
        hif[i] = (short)hu;
        lof[i] = (short)f2bf(lo);
      }
#pragma unroll
      for (int dt = 0; dt < 5; ++dt) {
        accPV[dt] = MFMA16(hif, vfr[ks][dt], accPV[dt], 0, 0, 0);
        accPV[dt] = MFMA16(lof, vfr[ks][dt], accPV[dt], 0, 0, 0);
      }
    }
    __builtin_amdgcn_wave_barrier();
    // rotate prefetched K into place
    if (c < 11) {
#pragma unroll
      for (int i = 0; i < 12; ++i) kf[i] = kfN[i];
    }
  }
#undef LOADK
  int b = bh >> 4, h = bh & 15;
  float amx = 0.f;
#pragma unroll
  for (int dt = 0; dt < 5; ++dt) {
#pragma unroll
    for (int r = 0; r < 4; ++r) {
      int q = qw + lg * 4 + r, d = dt * 16 + lr;
      if (q < cS && d < cD) {
        float av = accPV[dt][r] * sv;
        attn[((long)(b * cS + q)) * cE + h * cD + d] = av;
        amx = fmaxf(amx, fabsf(av));
      }
    }
  }
  for (int o = 32; o; o >>= 1) amx = fmaxf(amx, __shfl_xor(amx, o));
  if (lane == 0) atomicMax((unsigned int*)(scal + 9), __float_as_uint(amx));
}

// ---------------------------------------------------------------------------
extern "C" void kernel_launch(void* const* d_in, const int* in_sizes, int n_in,
                              void* d_out, int out_size, void* d_ws, size_t ws_size,
                              hipStream_t stream) {
  (void)in_sizes; (void)n_in; (void)out_size;
  if (ws_size < WS_TOTAL) return;

  const float* hs = (const float*)d_in[0];
  const float* wq = (const float*)d_in[1];
  const float* bq = (const float*)d_in[2];
  const float* wk = (const float*)d_in[3];
  const float* bk = (const float*)d_in[4];
  const float* wv = (const float*)d_in[5];
  const float* bv = (const float*)d_in[6];
  const float* wo = (const float*)d_in[7];
  const float* bo = (const float*)d_in[8];

  char* ws = (char*)d_ws;
  float* scal = (float*)(ws + B_SCAL);
  char* W2O  = ws + B_W2O;
  char* W2Q  = ws + B_W2Q;    // W2K, W2V follow contiguously
  char* A2   = ws + B_A2;
  ushort_t* vT = (ushort_t*)(ws + B_VT);
  ushort_t* qb = (ushort_t*)(ws + B_QB);
  ushort_t* kb = (ushort_t*)(ws + B_KB);
  float* rowM = (float*)(ws + B_ROWM);
  float* rowZ = (float*)(ws + B_ROWZ);

  float* outb = (float*)d_out;           // attn_output region (also attn scratch)
  float* Pout = outb + cQKV;             // attn_weights region (also Rq/Rk/Rv scratch)
  float* Rq = Pout;
  float* Rk = Pout + cQKV;
  float* Rv = Pout + 2 * cQKV;

  init_k<<<1, 64, 0, stream>>>(scal);

  // absmax of raw inputs
  absmax_k<<<1024, 256, 0, stream>>>((const float4*)hs, cQKV / 4, (unsigned int*)(scal + 0));
  absmax_k<<<512, 256, 0, stream>>>((const float4*)wq, cWN / 4, (unsigned int*)(scal + 1));
  absmax_k<<<512, 256, 0, stream>>>((const float4*)wk, cWN / 4, (unsigned int*)(scal + 2));
  absmax_k<<<512, 256, 0, stream>>>((const float4*)wv, cWN / 4, (unsigned int*)(scal + 3));
  absmax_k<<<512, 256, 0, stream>>>((const float4*)wo, cWN / 4, (unsigned int*)(scal + 4));

  // pack weights + hidden to i8 hi/lo planes
  pack8_k<<<324, 256, 0, stream>>>(wq, scal + 1, W2Q, cE);
  pack8_k<<<324, 256, 0, stream>>>(wk, scal + 2, W2Q + SZ_W2, cE);
  pack8_k<<<324, 256, 0, stream>>>(wv, scal + 3, W2Q + 2 * SZ_W2, cE);
  pack8_k<<<324, 256, 0, stream>>>(wo, scal + 4, W2O, cE);
  pack8_k<<<3312, 256, 0, stream>>>(hs, scal + 0, A2, cM);

  // merged Q/K/V projection (fused absmax -> slots 5,6,7)
  mgemm_k<0><<<dim3(9, 92, 3), 256, 0, stream>>>(A2, W2Q, bq, bk, bv, Rq, scal);

  // 8-bit integer-bf16 conversions for attention
  qk8_k<<<4096, 256, 0, stream>>>(Rq, qb, scal + 5);
  qk8_k<<<4096, 256, 0, stream>>>(Rk, kb, scal + 6);
  v8T_k<<<dim3(256, 12), 256, 0, stream>>>(Rv, vT, scal + 7);

  // attention
  qk_statsA<<<dim3(12, 256), 256, 0, stream>>>(qb, kb, scal, rowM, rowZ, (unsigned int*)(scal + 8));
  qk_pv<<<dim3(12, 256), 256, 0, stream>>>(qb, kb, vT, rowM, rowZ, scal, Pout, outb);

  // O projection: pack attn (slot 9 from qk_pv), GEMM -> final attn_output
  pack8_k<<<3312, 256, 0, stream>>>(outb, scal + 9, A2, cM);
  mgemm_k<1><<<dim3(9, 92, 1), 256, 0, stream>>>(A2, W2O, bo, bo, bo, outb, scal);
}

// Round 9
// 814.584 us; speedup vs baseline: 7.3838x; 1.1660x over previous
//
#include <hip/hip_runtime.h>
#include <cstdint>
#include <cstddef>

// ---------------------------------------------------------------------------
// SiglipAttention fake-quant.  B=16 S=729 E=1152 H=16 D=72.
// Outputs fp32: attn_output (B,S,E) then attn_weights (B,H,S,S).
// Round 9: statsA 64 rows/wave, qk_pv 32 rows/wave (in-place K prefetch),
//          consolidated absmax/packW/qk8 launches.
// ---------------------------------------------------------------------------

typedef unsigned short ushort_t;

constexpr int   cB = 16, cS = 729, cE = 1152, cH = 16, cD = 72;
constexpr int   cM = cB * cS;                    // 11664
constexpr long  cQKV  = (long)cM * cE;           // 13,436,928
constexpr long  cWN   = (long)cE * cE;           // 1,327,104
constexpr float cScale = 0.11785113019775792f;   // 72^-0.5
constexpr int   cSP = 768;                       // padded S rows for qb/kb
constexpr int   cDP96 = 96;                      // padded D for MFMA K
constexpr int   cVD = 80;                        // vT d-rows (72 used + 8 pad)
constexpr int   cMF = 11776;                     // padded M (92 tiles of 128)
constexpr int   cRB = 2304;                      // i8 row bytes: [h 1152 | l 1152]

// ---- workspace byte offsets (total ~147 MB <= proven 243.7 MB) -------------
constexpr size_t B_SCAL = 0;                                    // 16 f32
constexpr size_t SZ_W2  = (size_t)cE * cRB;                     // 2,654,208
constexpr size_t B_W2O  = 256;
constexpr size_t B_W2Q  = B_W2O + SZ_W2;                        // W2Q,K,V contiguous
constexpr size_t B_A2   = B_W2Q + 3 * SZ_W2;
constexpr size_t SZ_A2  = (size_t)cMF * cRB;                    // 27,131,904
constexpr size_t B_VT   = B_A2 + SZ_A2;
constexpr size_t SZ_VT  = (size_t)256 * cVD * cSP * 2;          // 31,457,280
constexpr size_t B_QB   = B_VT + SZ_VT;
constexpr size_t SZ_QB  = (size_t)256 * cSP * cDP96 * 2;        // 37,748,736
constexpr size_t B_KB   = B_QB + SZ_QB;
constexpr size_t B_ROWM = B_KB + SZ_QB;
constexpr size_t SZ_ROW = (size_t)256 * cS * 4;                 // 746,496
constexpr size_t B_ROWZ = B_ROWM + SZ_ROW;
constexpr size_t WS_TOTAL = B_ROWZ + SZ_ROW;
static_assert(WS_TOTAL <= 243689728, "stay under proven ws size");

// scalar slots: 0 hid,1 wq,2 wk,3 wv,4 wo,5 q,6 k,7 v,8 minZ,9 attn

typedef __attribute__((ext_vector_type(8))) short bf16x8;
typedef __attribute__((ext_vector_type(4))) float f32x4;
typedef __attribute__((ext_vector_type(4))) int   i32x4;
#define MFMA16 __builtin_amdgcn_mfma_f32_16x16x32_bf16
#define MFMAI8 __builtin_amdgcn_mfma_i32_16x16x64_i8

__device__ __forceinline__ unsigned short f2bf(float f) {
  unsigned u = __float_as_uint(f);
  return (unsigned short)((u + 0x7fffu + ((u >> 16) & 1u)) >> 16);   // RNE
}
__device__ __forceinline__ float bf2f(unsigned short h) {
  return __uint_as_float(((unsigned)h) << 16);
}
__device__ __forceinline__ void gload16(const void* g, void* l) {
  __builtin_amdgcn_global_load_lds((const __attribute__((address_space(1))) unsigned int*)g,
                                   (__attribute__((address_space(3))) unsigned int*)l, 16, 0, 0);
}

// ---------------------------------------------------------------------------
__global__ void init_k(float* sc) {
  int t = threadIdx.x;
  if (t < 16) sc[t] = (t == 8) ? __uint_as_float(0x7f800000u) : 0.0f;
}

// consolidated absmax over 5 tensors: blockIdx.y selects tensor -> scal[y]
__global__ __launch_bounds__(256) void absmax5_k(const float4* __restrict__ x0, const float4* __restrict__ x1,
                                                 const float4* __restrict__ x2, const float4* __restrict__ x3,
                                                 const float4* __restrict__ x4, unsigned int* __restrict__ scal) {
  int t = blockIdx.y;
  const float4* x = (t == 0) ? x0 : (t == 1) ? x1 : (t == 2) ? x2 : (t == 3) ? x3 : x4;
  long n4 = (t == 0) ? cQKV / 4 : cWN / 4;
  float m = 0.f;
  long i = (long)blockIdx.x * blockDim.x + threadIdx.x;
  long str = (long)gridDim.x * blockDim.x;
  for (; i < n4; i += str) {
    float4 v = x[i];
    m = fmaxf(m, fmaxf(fmaxf(fabsf(v.x), fabsf(v.y)), fmaxf(fabsf(v.z), fabsf(v.w))));
  }
  for (int o = 32; o; o >>= 1) m = fmaxf(m, __shfl_xor(m, o));
  __shared__ float red[4];
  int lane = threadIdx.x & 63, w = threadIdx.x >> 6;
  if (!lane) red[w] = m;
  __syncthreads();
  if (threadIdx.x == 0) {
    m = fmaxf(fmaxf(red[0], red[1]), fmaxf(red[2], red[3]));
    atomicMax(&scal[t], __float_as_uint(m));
  }
}

// ---------------------------------------------------------------------------
// fq16 -> integer n -> hi/lo i8 planes: n = 256*a + b (exact except clamp tail)
__global__ __launch_bounds__(256) void pack8_k(const float* __restrict__ src, const float* __restrict__ slot,
                                               char* __restrict__ dst, int nsrc) {
  float s = fmaxf(*slot, 1e-8f) / 32767.f;
  int i = blockIdx.x * 256 + threadIdx.x;
  int r = i / 72, c16 = i - r * 72;
  int m = (r < nsrc) ? r : nsrc - 1;
  const float4* p = (const float4*)(src + (long)m * cE + c16 * 16);
  float4 v[4] = {p[0], p[1], p[2], p[3]};
  const float* xv = (const float*)v;
  unsigned char hb[16] __attribute__((aligned(16)));
  unsigned char lb[16] __attribute__((aligned(16)));
#pragma unroll
  for (int j = 0; j < 16; ++j) {
    float t = rintf(xv[j] / s);
    t = fminf(fmaxf(t, -32767.f), 32767.f);
    float af = floorf(t * 0.00390625f + 0.5f);   // round-half-up to hi byte
    af = fminf(af, 127.f);
    float bf = t - 256.f * af;
    bf = fminf(fmaxf(bf, -128.f), 127.f);
    hb[j] = (unsigned char)((int)af & 0xff);
    lb[j] = (unsigned char)((int)bf & 0xff);
  }
  char* d = dst + (long)r * cRB + c16 * 16;
  *(uint4*)d = *(const uint4*)hb;
  *(uint4*)(d + 1152) = *(const uint4*)lb;
}

// consolidated weight pack: blockIdx.y = z (0 wq,1 wk,2 wv,3 wo)
__global__ __launch_bounds__(256) void packW4_k(const float* __restrict__ w0, const float* __restrict__ w1,
                                                const float* __restrict__ w2, const float* __restrict__ w3,
                                                const float* __restrict__ scal,
                                                char* __restrict__ W2Q, char* __restrict__ W2O) {
  int z = blockIdx.y;
  const float* src = (z == 0) ? w0 : (z == 1) ? w1 : (z == 2) ? w2 : w3;
  char* dst = (z < 3) ? (W2Q + (size_t)z * SZ_W2) : W2O;
  float s = fmaxf(scal[1 + z], 1e-8f) / 32767.f;
  int i = blockIdx.x * 256 + threadIdx.x;
  int r = i / 72, c16 = i - r * 72;
  const float4* p = (const float4*)(src + (long)r * cE + c16 * 16);
  float4 v[4] = {p[0], p[1], p[2], p[3]};
  const float* xv = (const float*)v;
  unsigned char hb[16] __attribute__((aligned(16)));
  unsigned char lb[16] __attribute__((aligned(16)));
#pragma unroll
  for (int j = 0; j < 16; ++j) {
    float t = rintf(xv[j] / s);
    t = fminf(fmaxf(t, -32767.f), 32767.f);
    float af = floorf(t * 0.00390625f + 0.5f);
    af = fminf(af, 127.f);
    float bf = t - 256.f * af;
    bf = fminf(fmaxf(bf, -128.f), 127.f);
    hb[j] = (unsigned char)((int)af & 0xff);
    lb[j] = (unsigned char)((int)bf & 0xff);
  }
  char* d = dst + (long)r * cRB + c16 * 16;
  *(uint4*)d = *(const uint4*)hb;
  *(uint4*)(d + 1152) = *(const uint4*)lb;
}

// ---------------------------------------------------------------------------
// int8 MFMA GEMM (unchanged, verified).
template <int OM>
__global__ __launch_bounds__(256, 2) void mgemm_k(const char* __restrict__ A2,
                                                  const char* __restrict__ W2base,
                                                  const float* __restrict__ b0, const float* __restrict__ b1,
                                                  const float* __restrict__ b2,
                                                  float* __restrict__ outbase, float* __restrict__ scal) {
  __shared__ char L[2][32768];
  int z = (OM == 0) ? blockIdx.z : 0;
  const char* W2 = W2base + (size_t)z * cE * cRB;
  const float* bias = (z == 0) ? b0 : (z == 1) ? b1 : b2;
  float* out = outbase + (long)z * cQKV;
  float sA = fmaxf(scal[OM == 0 ? 0 : 9], 1e-8f) / 32767.f;
  float sW = fmaxf(scal[OM == 0 ? 1 + z : 4], 1e-8f) / 32767.f;
  float sc = sA * sW;

  int tid = threadIdx.x, w = tid >> 6, lane = tid & 63;
  int lr = lane & 15, kc = lane >> 4;
  int mt = blockIdx.y * 128, nt = blockIdx.x * 128;
  int wr = (w >> 1) * 64, wc = (w & 1) * 64;

  bool isA = (w < 2);
  const char* mat = isA ? (A2 + (long)mt * cRB) : (W2 + (long)nt * cRB);
  const char* src[8];
  int ldo[8];
#pragma unroll
  for (int j = 0; j < 8; ++j) {
    int seg = (w & 1) * 8 + j;
    int o = seg * 1024 + lane * 16;
    int row = o >> 7, chs = (o >> 4) & 7, orig = chs ^ (row & 7);
    src[j] = mat + (long)row * cRB + (orig >> 2) * 1152 + (orig & 3) * 16;
    ldo[j] = (isA ? 0 : 16384) + seg * 1024;
  }

  int aoffH[4], aoffL[4], boffH[4], boffL[4];
#pragma unroll
  for (int i = 0; i < 4; ++i) {
    int ra = wr + i * 16 + lr;
    aoffH[i] = ra * 128 + ((kc ^ (ra & 7)) << 4);
    aoffL[i] = ra * 128 + (((kc + 4) ^ (ra & 7)) << 4);
    int rb = wc + i * 16 + lr;
    boffH[i] = 16384 + rb * 128 + ((kc ^ (rb & 7)) << 4);
    boffL[i] = 16384 + rb * 128 + (((kc + 4) ^ (rb & 7)) << 4);
  }

  auto stage = [&](int buf, int kk) {
#pragma unroll
    for (int j = 0; j < 8; ++j)
      gload16(src[j] + (long)kk * 64, &L[buf][ldo[j]]);
  };

  i32x4 P1[4][4] = {};
  i32x4 Pm[4][4] = {};
  stage(0, 0);
  __syncthreads();
  int cur = 0;
  for (int kk = 0; kk < 18; ++kk) {
    if (kk < 17) stage(cur ^ 1, kk + 1);
    i32x4 ah[4], al[4], whf[4], wlf[4];
#pragma unroll
    for (int i = 0; i < 4; ++i) {
      ah[i]  = *(const i32x4*)&L[cur][aoffH[i]];
      al[i]  = *(const i32x4*)&L[cur][aoffL[i]];
      whf[i] = *(const i32x4*)&L[cur][boffH[i]];
      wlf[i] = *(const i32x4*)&L[cur][boffL[i]];
    }
#pragma unroll
    for (int i = 0; i < 4; ++i)
#pragma unroll
      for (int j = 0; j < 4; ++j) {
        P1[i][j] = MFMAI8(ah[i], whf[j], P1[i][j], 0, 0, 0);
        Pm[i][j] = MFMAI8(ah[i], wlf[j], Pm[i][j], 0, 0, 0);
        Pm[i][j] = MFMAI8(al[i], whf[j], Pm[i][j], 0, 0, 0);
      }
    __syncthreads();
    cur ^= 1;
  }

  float amx = 0.f;
#pragma unroll
  for (int i = 0; i < 4; ++i) {
#pragma unroll
    for (int r = 0; r < 4; ++r) {
      int m = mt + wr + i * 16 + kc * 4 + r;
      if (m >= cM) continue;
      int b = m / cS, s = m - b * cS;
#pragma unroll
      for (int j = 0; j < 4; ++j) {
        int n = nt + wc + j * 16 + lr;
        float val = 65536.f * (float)P1[i][j][r] + 256.f * (float)Pm[i][j][r];
        float cv = sc * val + bias[n];
        if (OM == 1) {
          out[(long)m * cE + n] = cv;
        } else {
          int h = n / cD, d = n - h * cD;
          out[((long)(b * cH + h) * cS + s) * cD + d] = cv;
          amx = fmaxf(amx, fabsf(cv));
        }
      }
    }
  }
  if (OM == 0) {
    for (int o = 32; o; o >>= 1) amx = fmaxf(amx, __shfl_xor(amx, o));
    if (lane == 0) atomicMax((unsigned int*)(scal + 5 + z), __float_as_uint(amx));
  }
}

// ---------------------------------------------------------------------------
// q/k fp32 (bh,729,72) -> 8-bit integer as bf16 (bh,768,96); blockIdx.y = q/k
__global__ __launch_bounds__(256) void qk82_k(const float* __restrict__ Rq, const float* __restrict__ Rk,
                                              ushort_t* __restrict__ qb, ushort_t* __restrict__ kb,
                                              const float* __restrict__ scal) {
  int z = blockIdx.y;
  const float* src = z ? Rk : Rq;
  ushort_t* dst = z ? kb : qb;
  float s8 = fmaxf(scal[5 + z], 1e-8f) / 127.f;
  long total2 = (long)256 * cSP * cDP96 / 2;
  long i = (long)blockIdx.x * blockDim.x + threadIdx.x;
  long str = (long)gridDim.x * blockDim.x;
  for (; i < total2; i += str) {
    long e = i * 2;
    int d = (int)(e % cDP96);
    long rem = e / cDP96;
    int s = (int)(rem % cSP);
    int bh = (int)(rem / cSP);
    float v0 = 0.f, v1 = 0.f;
    if (s < cS && d < cD) {
      const float* p = src + ((long)bh * cS + s) * cD + d;
      v0 = p[0]; v1 = p[1];
    }
    float n0 = fminf(fmaxf(rintf(v0 / s8), -127.f), 127.f);
    float n1 = fminf(fmaxf(rintf(v1 / s8), -127.f), 127.f);
    ushort2 o; o.x = f2bf(n0); o.y = f2bf(n1);
    *(ushort2*)(dst + e) = o;
  }
}

// v fp32 (bh,729,72) -> transposed 8-bit integer bf16 vT (bh,80,768)
__global__ __launch_bounds__(256) void v8T_k(const float* __restrict__ vf, ushort_t* __restrict__ vT,
                                             const float* __restrict__ slot) {
  __shared__ float T[64][73];
  int bh = blockIdx.x, k0 = blockIdx.y * 64;
  int tid = threadIdx.x;
  float s8 = fmaxf(*slot, 1e-8f) / 127.f;
  for (int e = tid; e < 64 * 72; e += 256) {
    int r = e / 72, c = e - r * 72;
    T[r][c] = (k0 + r < cS) ? vf[((long)bh * cS + k0 + r) * cD + c] : 0.f;
  }
  __syncthreads();
  for (int e = tid; e < 64 * 80; e += 256) {
    int d = e >> 6, kk = e & 63;
    float val = (d < cD && k0 + kk < cS) ? T[kk][d] : 0.f;
    float n = fminf(fmaxf(rintf(val / s8), -127.f), 127.f);
    vT[((long)bh * cVD + d) * cSP + k0 + kk] = f2bf(n);
  }
}

// ---------------------------------------------------------------------------
// pass A: swapped mfma(K,Q) -> per-row m,Z; global min Z.  grid (3, 256)
// 64 q-rows per wave (4 tiles share each K fragment; 4 independent chains).
__global__ __launch_bounds__(256) void qk_statsA(const ushort_t* __restrict__ qb,
                                                 const ushort_t* __restrict__ kb,
                                                 const float* __restrict__ scal,
                                                 float* __restrict__ rowM, float* __restrict__ rowZ,
                                                 unsigned int* __restrict__ minZ) {
  int bh = blockIdx.y;
  int w = threadIdx.x >> 6, lane = threadIdx.x & 63;
  int lr = lane & 15, lg = lane >> 4;
  int q0 = blockIdx.x * 256 + w * 64;
  float f = (fmaxf(scal[5], 1e-8f) / 127.f) * (fmaxf(scal[6], 1e-8f) / 127.f) * cScale;
  bf16x8 qa[4][3];
#pragma unroll
  for (int ti = 0; ti < 4; ++ti) {
    const ushort_t* Qp = qb + ((long)bh * cSP + q0 + ti * 16 + lr) * cDP96 + lg * 8;
    qa[ti][0] = *(const bf16x8*)(Qp);
    qa[ti][1] = *(const bf16x8*)(Qp + 32);
    qa[ti][2] = *(const bf16x8*)(Qp + 64);
  }
  const ushort_t* Kp0 = kb + ((long)bh * cSP + lr) * cDP96 + lg * 8;
  float m[4] = {-INFINITY, -INFINITY, -INFINITY, -INFINITY};
  float z[4] = {0.f, 0.f, 0.f, 0.f};
  for (int k0 = 0; k0 < 736; k0 += 16) {
    const ushort_t* Kp = Kp0 + (long)k0 * cDP96;
    bf16x8 kA = *(const bf16x8*)(Kp);
    bf16x8 kB = *(const bf16x8*)(Kp + 32);
    bf16x8 kC = *(const bf16x8*)(Kp + 64);
    int kbase = k0 + lg * 4;
    bool v0 = kbase + 0 < cS, v1 = kbase + 1 < cS, v2 = kbase + 2 < cS, v3 = kbase + 3 < cS;
#pragma unroll
    for (int ti = 0; ti < 4; ++ti) {
      f32x4 acc = {0.f, 0.f, 0.f, 0.f};
      acc = MFMA16(kA, qa[ti][0], acc, 0, 0, 0);
      acc = MFMA16(kB, qa[ti][1], acc, 0, 0, 0);
      acc = MFMA16(kC, qa[ti][2], acc, 0, 0, 0);
      float l0 = v0 ? acc[0] * f : -INFINITY;
      float l1 = v1 ? acc[1] * f : -INFINITY;
      float l2 = v2 ? acc[2] * f : -INFINITY;
      float l3 = v3 ? acc[3] * f : -INFINITY;
      float tm = fmaxf(fmaxf(l0, l1), fmaxf(l2, l3));
      float mn = fmaxf(m[ti], tm);
      z[ti] = z[ti] * __expf(m[ti] - mn) + __expf(l0 - mn) + __expf(l1 - mn) + __expf(l2 - mn) + __expf(l3 - mn);
      m[ti] = mn;
    }
  }
  float zs = __uint_as_float(0x7f800000u);
#pragma unroll
  for (int ti = 0; ti < 4; ++ti) {
#pragma unroll
    for (int o = 16; o <= 32; o <<= 1) {
      float mo = __shfl_xor(m[ti], o);
      float zo = __shfl_xor(z[ti], o);
      float mn = fmaxf(m[ti], mo);
      z[ti] = z[ti] * __expf(m[ti] - mn) + zo * __expf(mo - mn);
      m[ti] = mn;
    }
    int q = q0 + ti * 16 + lr;
    if (lane < 16 && q < cS) {
      rowM[(long)bh * cS + q] = m[ti];
      rowZ[(long)bh * cS + q] = z[ti];
    }
    if (q < cS) zs = fminf(zs, z[ti]);
  }
#pragma unroll
  for (int o = 1; o < 16; o <<= 1) zs = fminf(zs, __shfl_xor(zs, o));
  if (lane == 0) atomicMin(minZ, __float_as_uint(zs));
}

// ---------------------------------------------------------------------------
// pass B fused, wave-independent, 32 q-rows per wave: P = fq16(softmax) -> P
// (nontemporal), attn = P @ v * sv, fused absmax(attn).  grid (6, 256)
__global__ __launch_bounds__(256) void qk_pv(const ushort_t* __restrict__ qb,
                                             const ushort_t* __restrict__ kb,
                                             const ushort_t* __restrict__ vT,
                                             const float* __restrict__ rowM, const float* __restrict__ rowZ,
                                             float* __restrict__ scal,
                                             float* __restrict__ P, float* __restrict__ attn) {
  __shared__ float Pt[4][32][68];   // per-wave slice, 2 tiles of 16 rows
  int qt = blockIdx.x, bh = blockIdx.y;
  int tid = threadIdx.x, w = tid >> 6, lane = tid & 63;
  int lr = lane & 15, lg = lane >> 4;
  int qw = qt * 128 + w * 32;
  float f = (fmaxf(scal[5], 1e-8f) / 127.f) * (fmaxf(scal[6], 1e-8f) / 127.f) * cScale;
  float sv = fmaxf(scal[7], 1e-8f) / 127.f;
  float sp = fmaxf(1.0f / scal[8], 1e-8f) / 32767.f;
  float mr[2][4], cr[2][4];
#pragma unroll
  for (int ti = 0; ti < 2; ++ti)
#pragma unroll
    for (int r = 0; r < 4; ++r) {
      int qq = qw + ti * 16 + lg * 4 + r;
      bool v = qq < cS;
      mr[ti][r] = v ? rowM[(long)bh * cS + qq] : 0.f;
      float Z = v ? rowZ[(long)bh * cS + qq] : 1.f;
      cr[ti][r] = v ? 1.0f / (Z * sp) : 0.f;
    }
  bf16x8 qa[2][3];
#pragma unroll
  for (int ti = 0; ti < 2; ++ti) {
    const ushort_t* Qp = qb + ((long)bh * cSP + qw + ti * 16 + lr) * cDP96 + lg * 8;
    qa[ti][0] = *(const bf16x8*)(Qp);
    qa[ti][1] = *(const bf16x8*)(Qp + 32);
    qa[ti][2] = *(const bf16x8*)(Qp + 64);
  }

  const ushort_t* Kbase = kb + (long)bh * cSP * cDP96 + (long)lr * cDP96 + lg * 8;
#define LOADK(dst, k0_)                                                        \
  do {                                                                         \
    _Pragma("unroll") for (int t = 0; t < 4; ++t)                              \
      _Pragma("unroll") for (int s = 0; s < 3; ++s)                            \
        dst[t * 3 + s] = *(const bf16x8*)(Kbase + ((long)((k0_) + t * 16)) * cDP96 + s * 32); \
  } while (0)

  bf16x8 kf[12];
  LOADK(kf, 0);
  f32x4 accPV[2][5] = {};
  for (int c = 0; c < 12; ++c) {
    int k0 = c * 64;
    // ---- QK: 4 n-tiles x 2 q-tiles
#pragma unroll
    for (int t = 0; t < 4; ++t) {
      f32x4 a0 = {0.f, 0.f, 0.f, 0.f};
      f32x4 a1 = {0.f, 0.f, 0.f, 0.f};
      a0 = MFMA16(qa[0][0], kf[t * 3 + 0], a0, 0, 0, 0);
      a1 = MFMA16(qa[1][0], kf[t * 3 + 0], a1, 0, 0, 0);
      a0 = MFMA16(qa[0][1], kf[t * 3 + 1], a0, 0, 0, 0);
      a1 = MFMA16(qa[1][1], kf[t * 3 + 1], a1, 0, 0, 0);
      a0 = MFMA16(qa[0][2], kf[t * 3 + 2], a0, 0, 0, 0);
      a1 = MFMA16(qa[1][2], kf[t * 3 + 2], a1, 0, 0, 0);
      bool kval = (k0 + t * 16 + lr) < cS;
#pragma unroll
      for (int r = 0; r < 4; ++r) {
        float e0 = __expf(a0[r] * f - mr[0][r]);
        float n0 = fminf(rintf(e0 * cr[0][r]), 32767.f);
        Pt[w][lg * 4 + r][t * 16 + lr] = kval ? n0 * sp : 0.f;
        float e1 = __expf(a1[r] * f - mr[1][r]);
        float n1 = fminf(rintf(e1 * cr[1][r]), 32767.f);
        Pt[w][16 + lg * 4 + r][t * 16 + lr] = kval ? n1 * sp : 0.f;
      }
    }
    __builtin_amdgcn_wave_barrier();
    // ---- prefetch next chunk's K in place (retires under P store + PV)
    if (c < 11) LOADK(kf, k0 + 64);
    // ---- P write: nontemporal (never re-read on device)
    if (k0 + 64 <= cS) {
#pragma unroll
      for (int it = 0; it < 8; ++it) {
        int e = it * 64 + lane;
        int row = e >> 4, c4 = e & 15;
        int q = qw + row;
        if (q < cS) {
          f32x4 pv4 = *(const f32x4*)&Pt[w][row][c4 * 4];
          __builtin_nontemporal_store(pv4, (f32x4*)&P[((long)bh * cS + q) * cS + k0 + c4 * 4]);
        }
      }
    } else {
      int ncol = cS - k0;
#pragma unroll 4
      for (int j = 0; j < 32; ++j) {
        int q = qw + j;
        if (q < cS && lane < ncol)
          __builtin_nontemporal_store(Pt[w][j][lane], &P[((long)bh * cS + q) * cS + k0 + lane]);
      }
    }
    __builtin_amdgcn_wave_barrier();
    // ---- PV: A = P rows (Dekker hi/lo bf16), B = vT
#pragma unroll
    for (int ks = 0; ks < 2; ++ks) {
      bf16x8 vf5[5];
#pragma unroll
      for (int dt = 0; dt < 5; ++dt)
        vf5[dt] = *(const bf16x8*)(vT + ((long)bh * cVD + dt * 16 + lr) * cSP + k0 + ks * 32 + lg * 8);
#pragma unroll
      for (int ti = 0; ti < 2; ++ti) {
        const float* prow = &Pt[w][ti * 16 + lr][ks * 32 + lg * 8];
        bf16x8 hif, lof;
#pragma unroll
        for (int i = 0; i < 8; ++i) {
          float p = prow[i];
          unsigned short hu = f2bf(p);
          float lo = p - bf2f(hu);
          hif[i] = (short)hu;
          lof[i] = (short)f2bf(lo);
        }
#pragma unroll
        for (int dt = 0; dt < 5; ++dt) {
          accPV[ti][dt] = MFMA16(hif, vf5[dt], accPV[ti][dt], 0, 0, 0);
          accPV[ti][dt] = MFMA16(lof, vf5[dt], accPV[ti][dt], 0, 0, 0);
        }
      }
    }
    __builtin_amdgcn_wave_barrier();
  }
#undef LOADK
  int b = bh >> 4, h = bh & 15;
  float amx = 0.f;
#pragma unroll
  for (int ti = 0; ti < 2; ++ti)
#pragma unroll
    for (int dt = 0; dt < 5; ++dt)
#pragma unroll
      for (int r = 0; r < 4; ++r) {
        int q = qw + ti * 16 + lg * 4 + r, d = dt * 16 + lr;
        if (q < cS && d < cD) {
          float av = accPV[ti][dt][r] * sv;
          attn[((long)(b * cS + q)) * cE + h * cD + d] = av;
          amx = fmaxf(amx, fabsf(av));
        }
      }
  for (int o = 32; o; o >>= 1) amx = fmaxf(amx, __shfl_xor(amx, o));
  if (lane == 0) atomicMax((unsigned int*)(scal + 9), __float_as_uint(amx));
}

// ---------------------------------------------------------------------------
extern "C" void kernel_launch(void* const* d_in, const int* in_sizes, int n_in,
                              void* d_out, int out_size, void* d_ws, size_t ws_size,
                              hipStream_t stream) {
  (void)in_sizes; (void)n_in; (void)out_size;
  if (ws_size < WS_TOTAL) return;

  const float* hs = (const float*)d_in[0];
  const float* wq = (const float*)d_in[1];
  const float* bq = (const float*)d_in[2];
  const float* wk = (const float*)d_in[3];
  const float* bk = (const float*)d_in[4];
  const float* wv = (const float*)d_in[5];
  const float* bv = (const float*)d_in[6];
  const float* wo = (const float*)d_in[7];
  const float* bo = (const float*)d_in[8];

  char* ws = (char*)d_ws;
  float* scal = (float*)(ws + B_SCAL);
  char* W2O  = ws + B_W2O;
  char* W2Q  = ws + B_W2Q;    // W2K, W2V follow contiguously
  char* A2   = ws + B_A2;
  ushort_t* vT = (ushort_t*)(ws + B_VT);
  ushort_t* qb = (ushort_t*)(ws + B_QB);
  ushort_t* kb = (ushort_t*)(ws + B_KB);
  float* rowM = (float*)(ws + B_ROWM);
  float* rowZ = (float*)(ws + B_ROWZ);

  float* outb = (float*)d_out;           // attn_output region (also attn scratch)
  float* Pout = outb + cQKV;             // attn_weights region (also Rq/Rk/Rv scratch)
  float* Rq = Pout;
  float* Rk = Pout + cQKV;
  float* Rv = Pout + 2 * cQKV;

  init_k<<<1, 64, 0, stream>>>(scal);

  // absmax of all raw inputs (one launch)
  absmax5_k<<<dim3(512, 5), 256, 0, stream>>>((const float4*)hs, (const float4*)wq, (const float4*)wk,
                                              (const float4*)wv, (const float4*)wo, (unsigned int*)scal);

  // pack weights (one launch) + hidden to i8 hi/lo planes
  packW4_k<<<dim3(324, 4), 256, 0, stream>>>(wq, wk, wv, wo, scal, W2Q, W2O);
  pack8_k<<<3312, 256, 0, stream>>>(hs, scal + 0, A2, cM);

  // merged Q/K/V projection (fused absmax -> slots 5,6,7)
  mgemm_k<0><<<dim3(9, 92, 3), 256, 0, stream>>>(A2, W2Q, bq, bk, bv, Rq, scal);

  // 8-bit integer-bf16 conversions for attention
  qk82_k<<<dim3(4096, 2), 256, 0, stream>>>(Rq, Rk, qb, kb, scal);
  v8T_k<<<dim3(256, 12), 256, 0, stream>>>(Rv, vT, scal + 7);

  // attention
  qk_statsA<<<dim3(3, 256), 256, 0, stream>>>(qb, kb, scal, rowM, rowZ, (unsigned int*)(scal + 8));
  qk_pv<<<dim3(6, 256), 256, 0, stream>>>(qb, kb, vT, rowM, rowZ, scal, Pout, outb);

  // O projection: pack attn (slot 9 from qk_pv), GEMM -> final attn_output
  pack8_k<<<3312, 256, 0, stream>>>(outb, scal + 9, A2, cM);
  mgemm_k<1><<<dim3(9, 92, 1), 256, 0, stream>>>(A2, W2O, bo, bo, bo, outb, scal);
}